// Round 3
// baseline (3418.718 us; speedup 1.0000x reference)
//
#include <hip/hip_runtime.h>

#define NEG_SLOPE 0.2f

static constexpr int Hh  = 4;
static constexpr int Nn  = 50000;
static constexpr int Ee  = 1600000;
static constexpr int D   = 32;
static constexpr int BW  = 64;                       // bucket width (nodes)
static constexpr int BPH = (Nn + BW - 1) / BW;       // 782 buckets per head
static constexpr int NB  = Hh * BPH;                 // 3128 buckets total

// ---------------------------------------------------------------------------
// Kernel 1: xl = x @ W_l, xr = x @ W_r per head. 8 nodes x 32 ch per block.
// ---------------------------------------------------------------------------
__global__ void transform_kernel(const float* __restrict__ x,
                                 const float* __restrict__ Wl,
                                 const float* __restrict__ Wr,
                                 float* __restrict__ xl,
                                 float* __restrict__ xr) {
    __shared__ float wl_s[D * D];
    __shared__ float wr_s[D * D];
    const int h   = blockIdx.y;
    const int tid = threadIdx.x;
    for (int i = tid; i < D * D; i += 256) {
        wl_s[i] = Wl[h * D * D + i];
        wr_s[i] = Wr[h * D * D + i];
    }
    __syncthreads();

    const int node = blockIdx.x * 8 + (tid >> 5);
    const int c    = tid & 31;
    if (node >= Nn) return;

    const float* xrow = x + ((size_t)h * Nn + node) * D;
    float al = 0.f, ar = 0.f;
#pragma unroll
    for (int k = 0; k < D; ++k) {
        const float xv = xrow[k];
        al = fmaf(xv, wl_s[k * D + c], al);
        ar = fmaf(xv, wr_s[k * D + c], ar);
    }
    const size_t o = ((size_t)h * Nn + node) * D + c;
    xl[o] = al;
    xr[o] = ar;
}

// ---------------------------------------------------------------------------
// Bucket histogram: counts per (head, dst>>6). 3128 int counters, L2-resident.
// ---------------------------------------------------------------------------
__global__ void bhist_kernel(const int* __restrict__ ei, int* __restrict__ bcnt) {
    const int e = blockIdx.x * 256 + threadIdx.x;
    const int h = blockIdx.y;
    if (e >= Ee) return;
    const int dst = ei[(size_t)h * 2 * Ee + Ee + e];
    atomicAdd(&bcnt[h * BPH + (dst >> 6)], 1);
}

// ---------------------------------------------------------------------------
// Exclusive scan over NB=3128 bucket counts. Single block, chunked H-S scan.
// ---------------------------------------------------------------------------
__global__ void bscan_kernel(const int* __restrict__ bcnt,
                             int* __restrict__ boff, int* __restrict__ bcur) {
    __shared__ int s[1024];
    __shared__ int carry;
    const int tid = threadIdx.x;
    if (tid == 0) carry = 0;
    __syncthreads();
    for (int base = 0; base < NB; base += 1024) {
        const int i = base + tid;
        const int v = (i < NB) ? bcnt[i] : 0;
        s[tid] = v;
        __syncthreads();
        for (int o = 1; o < 1024; o <<= 1) {
            const int t = (tid >= o) ? s[tid - o] : 0;
            __syncthreads();
            s[tid] += t;
            __syncthreads();
        }
        if (i < NB) {
            const int excl = s[tid] - v + carry;
            boff[i] = excl;
            bcur[i] = excl;
        }
        __syncthreads();
        if (tid == 0) carry += s[1023];
        __syncthreads();
    }
}

// ---------------------------------------------------------------------------
// Binning scatter: place packed (src<<6 | dst&63) into the dst-bucket segment.
// Positions within a bucket are handed out sequentially -> write lines fill
// completely (3128 open segments x 64B = 200KB active front, L2-resident).
// ---------------------------------------------------------------------------
__global__ void bscatter_kernel(const int* __restrict__ ei, int* __restrict__ bcur,
                                unsigned* __restrict__ seg) {
    const int e = blockIdx.x * 256 + threadIdx.x;
    const int h = blockIdx.y;
    if (e >= Ee) return;
    const int src = ei[(size_t)h * 2 * Ee + e];
    const int dst = ei[(size_t)h * 2 * Ee + Ee + e];
    const int pos = atomicAdd(&bcur[h * BPH + (dst >> 6)], 1);
    seg[pos] = ((unsigned)src << 6) | (unsigned)(dst & 63);
}

// ---------------------------------------------------------------------------
// Accum: one block per bucket (64 dst nodes). Accumulator + xr tile in LDS;
// per-edge LDS atomicAdd (2-way bank alias = free). Epilogue fuses self-loop,
// divide, bias; single coalesced store per row. No global atomics.
// ---------------------------------------------------------------------------
__global__ void accum_kernel(const int* __restrict__ boff, const int* __restrict__ bcnt,
                             const unsigned* __restrict__ seg,
                             const float* __restrict__ xl, const float* __restrict__ xr,
                             const float* __restrict__ att, const float* __restrict__ bias,
                             float* __restrict__ out) {
    __shared__ float xr_s[BW * D];
    __shared__ float acc_s[BW * D];
    __shared__ float den_s[BW];

    const int blk = blockIdx.x;
    const int h   = blk / BPH;
    const int b   = blk - h * BPH;
    const int base  = b * BW;
    const int nrows = (Nn - base) < BW ? (Nn - base) : BW;

    const int tid = threadIdx.x;
    const int c   = tid & 31;
    const int hw  = tid >> 5;          // 8 half-waves per block

    for (int r = hw; r < BW; r += 8) {
        acc_s[r * D + c] = 0.f;
        xr_s[r * D + c]  = (r < nrows) ? xr[((size_t)h * Nn + base + r) * D + c] : 0.f;
    }
    if (tid < BW) den_s[tid] = 0.f;
    __syncthreads();

    const float attc = att[h * D + c];
    const int beg = boff[blk];
    const int end = beg + bcnt[blk];

    int e = beg + hw;
    unsigned pk = (e < end) ? seg[e] : 0u;
    while (e < end) {
        const int en = e + 8;
        const unsigned pkn = (en < end) ? seg[en] : 0u;   // prefetch next entry

        const int src = (int)(pk >> 6);
        const int ld  = (int)(pk & 63u);
        const float xls = xl[((size_t)h * Nn + src) * D + c];
        const float hv  = xls + xr_s[ld * D + c];
        const float lv  = hv > 0.f ? hv : NEG_SLOPE * hv;
        float p = lv * attc;
#pragma unroll
        for (int o = 16; o; o >>= 1) p += __shfl_xor(p, o);
        const float w = __expf(p);
        atomicAdd(&acc_s[ld * D + c], w * xls);
        if (c == 0) atomicAdd(&den_s[ld], w);

        pk = pkn;
        e  = en;
    }
    __syncthreads();

    // epilogue: self-loop + divide + bias
    for (int r = hw; r < nrows; r += 8) {
        const int n = base + r;
        const float xld = xl[((size_t)h * Nn + n) * D + c];
        const float hv  = xld + xr_s[r * D + c];
        const float lv  = hv > 0.f ? hv : NEG_SLOPE * hv;
        float p = lv * attc;
#pragma unroll
        for (int o = 16; o; o >>= 1) p += __shfl_xor(p, o);
        const float w = __expf(p);
        const float num = acc_s[r * D + c] + w * xld;
        const float den = den_s[r] + w;
        out[(size_t)n * (Hh * D) + h * D + c] = num / den + bias[h * D + c];
    }
}

extern "C" void kernel_launch(void* const* d_in, const int* in_sizes, int n_in,
                              void* d_out, int out_size, void* d_ws, size_t ws_size,
                              hipStream_t stream) {
    const float* x    = (const float*)d_in[0];
    const int*   ei   = (const int*)d_in[1];
    const float* Wl   = (const float*)d_in[2];
    const float* Wr   = (const float*)d_in[3];
    const float* att  = (const float*)d_in[4];
    const float* bias = (const float*)d_in[5];
    float* out = (float*)d_out;

    // workspace: xl[H*N*D] | xr[H*N*D] | seg[H*E] | bcnt[NB] | boff[NB] | bcur[NB]
    float*    xl   = (float*)d_ws;
    float*    xr   = xl + (size_t)Hh * Nn * D;
    unsigned* seg  = (unsigned*)(xr + (size_t)Hh * Nn * D);
    int*      bcnt = (int*)(seg + (size_t)Hh * Ee);
    int*      boff = bcnt + NB;
    int*      bcur = boff + NB;

    hipMemsetAsync(bcnt, 0, NB * sizeof(int), stream);

    dim3 gT((Nn + 7) / 8, Hh);
    transform_kernel<<<gT, 256, 0, stream>>>(x, Wl, Wr, xl, xr);

    dim3 gE((Ee + 255) / 256, Hh);
    bhist_kernel<<<gE, 256, 0, stream>>>(ei, bcnt);

    bscan_kernel<<<1, 1024, 0, stream>>>(bcnt, boff, bcur);

    bscatter_kernel<<<gE, 256, 0, stream>>>(ei, bcur, seg);

    accum_kernel<<<NB, 256, 0, stream>>>(boff, bcnt, seg, xl, xr, att, bias, out);
}

// Round 4
// 1947.850 us; speedup vs baseline: 1.7551x; 1.7551x over previous
//
#include <hip/hip_runtime.h>

#define NEG_SLOPE 0.2f

static constexpr int Hh  = 4;
static constexpr int Nn  = 50000;
static constexpr int Ee  = 1600000;
static constexpr int D   = 32;
static constexpr int BW  = 64;                       // bucket width (nodes)
static constexpr int BPH = (Nn + BW - 1) / BW;       // 782 buckets per head
static constexpr int NB  = Hh * BPH;                 // 3128 buckets total
static constexpr int P   = 16;                       // partitions per bucket
static constexpr int NBP = NB * P;                   // 50048 sub-segments
static constexpr int SB  = (NBP + 1023) / 1024;      // 49 scan blocks
static constexpr int RS  = 36;                       // padded LDS row stride (floats)

// ---------------------------------------------------------------------------
// Kernel 1: xl = x @ W_l, xr = x @ W_r per head. 8 nodes x 32 ch per block.
// ---------------------------------------------------------------------------
__global__ void transform_kernel(const float* __restrict__ x,
                                 const float* __restrict__ Wl,
                                 const float* __restrict__ Wr,
                                 float* __restrict__ xl,
                                 float* __restrict__ xr) {
    __shared__ float wl_s[D * D];
    __shared__ float wr_s[D * D];
    const int h   = blockIdx.y;
    const int tid = threadIdx.x;
    for (int i = tid; i < D * D; i += 256) {
        wl_s[i] = Wl[h * D * D + i];
        wr_s[i] = Wr[h * D * D + i];
    }
    __syncthreads();

    const int node = blockIdx.x * 8 + (tid >> 5);
    const int c    = tid & 31;
    if (node >= Nn) return;

    const float* xrow = x + ((size_t)h * Nn + node) * D;
    float al = 0.f, ar = 0.f;
#pragma unroll
    for (int k = 0; k < D; ++k) {
        const float xv = xrow[k];
        al = fmaf(xv, wl_s[k * D + c], al);
        ar = fmaf(xv, wr_s[k * D + c], ar);
    }
    const size_t o = ((size_t)h * Nn + node) * D + c;
    xl[o] = al;
    xr[o] = ar;
}

// ---------------------------------------------------------------------------
// Bucket histogram, partitioned: counter = bin*16 + (blockIdx&15).
// 50048 counters -> ~132 ops/counter (vs 2100 unpartitioned).
// ---------------------------------------------------------------------------
__global__ void bhist_kernel(const int* __restrict__ ei, int* __restrict__ bcnt) {
    const int e = blockIdx.x * 256 + threadIdx.x;
    const int h = blockIdx.y;
    if (e >= Ee) return;
    const int dst = ei[(size_t)h * 2 * Ee + Ee + e];
    const int p   = blockIdx.x & (P - 1);
    atomicAdd(&bcnt[(h * BPH + (dst >> 6)) * P + p], 1);
}

// --------------------------- 3-pass exclusive scan over NBP ----------------
__global__ void scan1_kernel(const int* __restrict__ bcnt, int* __restrict__ bsum) {
    __shared__ int s[1024];
    const int tid = threadIdx.x;
    const int i   = blockIdx.x * 1024 + tid;
    s[tid] = (i < NBP) ? bcnt[i] : 0;
    __syncthreads();
    for (int o = 512; o; o >>= 1) {
        if (tid < o) s[tid] += s[tid + o];
        __syncthreads();
    }
    if (tid == 0) bsum[blockIdx.x] = s[0];
}

__global__ void scan2_kernel(int* __restrict__ bsum) {
    __shared__ int s[64];
    const int tid = threadIdx.x;
    s[tid] = (tid < SB) ? bsum[tid] : 0;
    __syncthreads();
    for (int o = 1; o < 64; o <<= 1) {
        const int t = (tid >= o) ? s[tid - o] : 0;
        __syncthreads();
        s[tid] += t;
        __syncthreads();
    }
    if (tid < SB) bsum[tid] = tid ? s[tid - 1] : 0;
}

__global__ void scan3_kernel(const int* __restrict__ bcnt, const int* __restrict__ bsum,
                             int* __restrict__ boff, int* __restrict__ bcur) {
    __shared__ int s[1024];
    const int tid = threadIdx.x;
    const int i   = blockIdx.x * 1024 + tid;
    const int v   = (i < NBP) ? bcnt[i] : 0;
    s[tid] = v;
    __syncthreads();
    for (int o = 1; o < 1024; o <<= 1) {
        const int t = (tid >= o) ? s[tid - o] : 0;
        __syncthreads();
        s[tid] += t;
        __syncthreads();
    }
    if (i < NBP) {
        const int ex = s[tid] - v + bsum[blockIdx.x];
        boff[i] = ex;
        bcur[i] = ex;
    }
}

// ---------------------------------------------------------------------------
// Partitioned binning scatter. Sub-segments of a bucket are adjacent, so each
// bucket's edges stay contiguous in seg[].
// ---------------------------------------------------------------------------
__global__ void bscatter_kernel(const int* __restrict__ ei, int* __restrict__ bcur,
                                unsigned* __restrict__ seg) {
    const int e = blockIdx.x * 256 + threadIdx.x;
    const int h = blockIdx.y;
    if (e >= Ee) return;
    const int src = ei[(size_t)h * 2 * Ee + e];
    const int dst = ei[(size_t)h * 2 * Ee + Ee + e];
    const int p   = blockIdx.x & (P - 1);
    const int pos = atomicAdd(&bcur[(h * BPH + (dst >> 6)) * P + p], 1);
    seg[pos] = ((unsigned)src << 6) | (unsigned)(dst & 63);
}

// ---------------------------------------------------------------------------
// Accum: one block per bucket. 8 lanes x float4 per edge (8 edges/wave/iter),
// depth-2 pipelined seg + xl gathers, padded LDS rows (stride 36) to spread
// banks. Epilogue fuses self-loop + divide + bias.
// ---------------------------------------------------------------------------
__global__ void accum_kernel(const int* __restrict__ boff, const int* __restrict__ bcnt,
                             const unsigned* __restrict__ seg,
                             const float* __restrict__ xl, const float* __restrict__ xr,
                             const float* __restrict__ att, const float* __restrict__ bias,
                             float* __restrict__ out) {
    __shared__ __align__(16) float xr_s[BW * RS];
    __shared__ float acc_s[BW * RS];
    __shared__ float den_s[BW];
    __shared__ int   cnt_sh;

    const int blk   = blockIdx.x;
    const int h     = blk / BPH;
    const int b     = blk - h * BPH;
    const int base  = b * BW;
    const int nrows = (Nn - base) < BW ? (Nn - base) : BW;

    const int tid  = threadIdx.x;
    const int lane = tid & 63;
    const int wv   = tid >> 6;      // wave 0..3
    const int g    = lane >> 3;     // edge group 0..7 within wave
    const int l8   = lane & 7;      // lane within group (4 channels each)
    const int c    = tid & 31;
    const int hw   = tid >> 5;

    for (int r = hw; r < BW; r += 8) {
        acc_s[r * RS + c] = 0.f;
        xr_s[r * RS + c]  = (r < nrows) ? xr[((size_t)h * Nn + base + r) * D + c] : 0.f;
    }
    if (tid < BW) den_s[tid] = 0.f;
    if (tid == 0) {
        int s = 0;
#pragma unroll
        for (int p = 0; p < P; ++p) s += bcnt[blk * P + p];
        cnt_sh = s;
    }
    __syncthreads();

    const int beg = boff[blk * P];
    const int cnt = cnt_sh;
    const int end = beg + cnt;

    const float4  a4  = ((const float4*)att)[h * 8 + l8];
    const float4* xl4 = (const float4*)xl;
    const float4* xr4 = (const float4*)xr_s;    // row stride = 9 float4s

    const int nIter = (cnt + 31) >> 5;
    int e = beg + wv * 8 + g;
    unsigned pk0 = (e      < end) ? seg[e]      : 0u;
    unsigned pk1 = (e + 32 < end) ? seg[e + 32] : 0u;
    float4 x0 = xl4[((size_t)h * Nn + (pk0 >> 6)) * 8 + l8];

    for (int it = 0; it < nIter; ++it) {
        const unsigned pk2 = (e + 64 < end) ? seg[e + 64] : 0u;     // prefetch seg
        const float4   x1  = xl4[((size_t)h * Nn + (pk1 >> 6)) * 8 + l8]; // prefetch gather

        const int    ld = (int)(pk0 & 63u);
        const float4 r  = xr4[ld * 9 + l8];
        float4 hv;
        hv.x = x0.x + r.x; hv.y = x0.y + r.y; hv.z = x0.z + r.z; hv.w = x0.w + r.w;
        float4 lv;
        lv.x = fmaxf(hv.x, 0.f) + NEG_SLOPE * fminf(hv.x, 0.f);
        lv.y = fmaxf(hv.y, 0.f) + NEG_SLOPE * fminf(hv.y, 0.f);
        lv.z = fmaxf(hv.z, 0.f) + NEG_SLOPE * fminf(hv.z, 0.f);
        lv.w = fmaxf(hv.w, 0.f) + NEG_SLOPE * fminf(hv.w, 0.f);
        float p = lv.x * a4.x + lv.y * a4.y + lv.z * a4.z + lv.w * a4.w;
        p += __shfl_xor(p, 4);
        p += __shfl_xor(p, 2);
        p += __shfl_xor(p, 1);
        const float w = __expf(p);
        if (e < end) {
            float* ap = &acc_s[ld * RS + l8 * 4];
            atomicAdd(ap + 0, w * x0.x);
            atomicAdd(ap + 1, w * x0.y);
            atomicAdd(ap + 2, w * x0.z);
            atomicAdd(ap + 3, w * x0.w);
            if (l8 == 0) atomicAdd(&den_s[ld], w);
        }
        pk0 = pk1; pk1 = pk2; x0 = x1; e += 32;
    }
    __syncthreads();

    // epilogue: self-loop + divide + bias (half-wave per row, lane = channel)
    const float attc = att[h * D + c];
    for (int r = hw; r < nrows; r += 8) {
        const int n = base + r;
        const float xld = xl[((size_t)h * Nn + n) * D + c];
        const float hv  = xld + xr_s[r * RS + c];
        const float lvv = hv > 0.f ? hv : NEG_SLOPE * hv;
        float p = lvv * attc;
#pragma unroll
        for (int o = 16; o; o >>= 1) p += __shfl_xor(p, o);
        const float w   = __expf(p);
        const float num = acc_s[r * RS + c] + w * xld;
        const float den = den_s[r] + w;
        out[(size_t)n * (Hh * D) + h * D + c] = num / den + bias[h * D + c];
    }
}

extern "C" void kernel_launch(void* const* d_in, const int* in_sizes, int n_in,
                              void* d_out, int out_size, void* d_ws, size_t ws_size,
                              hipStream_t stream) {
    const float* x    = (const float*)d_in[0];
    const int*   ei   = (const int*)d_in[1];
    const float* Wl   = (const float*)d_in[2];
    const float* Wr   = (const float*)d_in[3];
    const float* att  = (const float*)d_in[4];
    const float* bias = (const float*)d_in[5];
    float* out = (float*)d_out;

    // workspace: xl[H*N*D] | xr[H*N*D] | seg[H*E] | bcnt[NBP] | boff[NBP] | bcur[NBP] | bsum[SB]
    float*    xl   = (float*)d_ws;
    float*    xr   = xl + (size_t)Hh * Nn * D;
    unsigned* seg  = (unsigned*)(xr + (size_t)Hh * Nn * D);
    int*      bcnt = (int*)(seg + (size_t)Hh * Ee);
    int*      boff = bcnt + NBP;
    int*      bcur = boff + NBP;
    int*      bsum = bcur + NBP;

    hipMemsetAsync(bcnt, 0, NBP * sizeof(int), stream);

    dim3 gT((Nn + 7) / 8, Hh);
    transform_kernel<<<gT, 256, 0, stream>>>(x, Wl, Wr, xl, xr);

    dim3 gE((Ee + 255) / 256, Hh);
    bhist_kernel<<<gE, 256, 0, stream>>>(ei, bcnt);

    scan1_kernel<<<SB, 1024, 0, stream>>>(bcnt, bsum);
    scan2_kernel<<<1, 64, 0, stream>>>(bsum);
    scan3_kernel<<<SB, 1024, 0, stream>>>(bcnt, bsum, boff, bcur);

    bscatter_kernel<<<gE, 256, 0, stream>>>(ei, bcur, seg);

    accum_kernel<<<NB, 256, 0, stream>>>(boff, bcnt, seg, xl, xr, att, bias, out);
}

// Round 5
// 910.440 us; speedup vs baseline: 3.7550x; 2.1395x over previous
//
#include <hip/hip_runtime.h>

#define NEG_SLOPE 0.2f

static constexpr int Hh   = 4;
static constexpr int Nn   = 50000;
static constexpr int Ee   = 1600000;
static constexpr int D    = 32;
static constexpr int BW   = 64;                       // bucket width (nodes)
static constexpr int BPH  = (Nn + BW - 1) / BW;       // 782 buckets per head
static constexpr int NB   = Hh * BPH;                 // 3128 buckets
static constexpr int P    = 16;                       // partitions per bucket
static constexpr int NBP  = NB * P;                   // 50048 sub-segments
static constexpr int SB   = (NBP + 1023) / 1024;      // 49 scan blocks
static constexpr int NR   = Hh * Nn;                  // 200000 rows
static constexpr int TOTE = Hh * Ee;                  // 6.4M edges

// ---------------------------------------------------------------------------
// xl = x @ W_l, xr = x @ W_r per head. 8 nodes x 32 ch per block.
// ---------------------------------------------------------------------------
__global__ void transform_kernel(const float* __restrict__ x,
                                 const float* __restrict__ Wl,
                                 const float* __restrict__ Wr,
                                 float* __restrict__ xl,
                                 float* __restrict__ xr) {
    __shared__ float wl_s[D * D];
    __shared__ float wr_s[D * D];
    const int h   = blockIdx.y;
    const int tid = threadIdx.x;
    for (int i = tid; i < D * D; i += 256) {
        wl_s[i] = Wl[h * D * D + i];
        wr_s[i] = Wr[h * D * D + i];
    }
    __syncthreads();

    const int node = blockIdx.x * 8 + (tid >> 5);
    const int c    = tid & 31;
    if (node >= Nn) return;

    const float* xrow = x + ((size_t)h * Nn + node) * D;
    float al = 0.f, ar = 0.f;
#pragma unroll
    for (int k = 0; k < D; ++k) {
        const float xv = xrow[k];
        al = fmaf(xv, wl_s[k * D + c], al);
        ar = fmaf(xv, wr_s[k * D + c], ar);
    }
    const size_t o = ((size_t)h * Nn + node) * D + c;
    xl[o] = al;
    xr[o] = ar;
}

// ---------------------------------------------------------------------------
// Bucket histogram, partitioned: counter = bin*P + (blockIdx&(P-1)).
// ---------------------------------------------------------------------------
__global__ void bhist_kernel(const int* __restrict__ ei, int* __restrict__ bcnt) {
    const int e = blockIdx.x * 256 + threadIdx.x;
    const int h = blockIdx.y;
    if (e >= Ee) return;
    const int dst = ei[(size_t)h * 2 * Ee + Ee + e];
    const int p   = blockIdx.x & (P - 1);
    atomicAdd(&bcnt[(h * BPH + (dst >> 6)) * P + p], 1);
}

// --------------------------- 3-pass exclusive scan over NBP ----------------
__global__ void scan1_kernel(const int* __restrict__ bcnt, int* __restrict__ bsum) {
    __shared__ int s[1024];
    const int tid = threadIdx.x;
    const int i   = blockIdx.x * 1024 + tid;
    s[tid] = (i < NBP) ? bcnt[i] : 0;
    __syncthreads();
    for (int o = 512; o; o >>= 1) {
        if (tid < o) s[tid] += s[tid + o];
        __syncthreads();
    }
    if (tid == 0) bsum[blockIdx.x] = s[0];
}

__global__ void scan2_kernel(int* __restrict__ bsum) {
    __shared__ int s[64];
    const int tid = threadIdx.x;
    s[tid] = (tid < SB) ? bsum[tid] : 0;
    __syncthreads();
    for (int o = 1; o < 64; o <<= 1) {
        const int t = (tid >= o) ? s[tid - o] : 0;
        __syncthreads();
        s[tid] += t;
        __syncthreads();
    }
    if (tid < SB) bsum[tid] = tid ? s[tid - 1] : 0;
}

__global__ void scan3_kernel(const int* __restrict__ bcnt, const int* __restrict__ bsum,
                             int* __restrict__ boff, int* __restrict__ bcur) {
    __shared__ int s[1024];
    const int tid = threadIdx.x;
    const int i   = blockIdx.x * 1024 + tid;
    const int v   = (i < NBP) ? bcnt[i] : 0;
    s[tid] = v;
    __syncthreads();
    for (int o = 1; o < 1024; o <<= 1) {
        const int t = (tid >= o) ? s[tid - o] : 0;
        __syncthreads();
        s[tid] += t;
        __syncthreads();
    }
    if (i < NBP) {
        const int ex = s[tid] - v + bsum[blockIdx.x];
        boff[i] = ex;
        bcur[i] = ex;
    }
}

// ---------------------------------------------------------------------------
// Partitioned binning scatter -> seg[] packed (src<<6 | dst&63), bucket-grouped.
// ---------------------------------------------------------------------------
__global__ void bscatter_kernel(const int* __restrict__ ei, int* __restrict__ bcur,
                                unsigned* __restrict__ seg) {
    const int e = blockIdx.x * 256 + threadIdx.x;
    const int h = blockIdx.y;
    if (e >= Ee) return;
    const int src = ei[(size_t)h * 2 * Ee + e];
    const int dst = ei[(size_t)h * 2 * Ee + Ee + e];
    const int p   = blockIdx.x & (P - 1);
    const int pos = atomicAdd(&bcur[(h * BPH + (dst >> 6)) * P + p], 1);
    seg[pos] = ((unsigned)src << 6) | (unsigned)(dst & 63);
}

// ---------------------------------------------------------------------------
// Local sort: one block per bucket. LDS 64-row histogram + wave-0 shfl scan,
// then scatter src (ushort) into per-row order within the bucket's contiguous
// window (~4KB, L2-perfect). Emits rowoff[] (global per-row CSR offsets).
// ---------------------------------------------------------------------------
__global__ void rowsort_kernel(const int* __restrict__ boff, const unsigned* __restrict__ seg,
                               unsigned short* __restrict__ seg2, int* __restrict__ rowoff) {
    __shared__ int rcnt[BW];
    __shared__ int rcur[BW];
    const int blk = blockIdx.x;
    const int tid = threadIdx.x;
    const int bb  = boff[blk * P];
    const int be  = (blk + 1 < NB) ? boff[(blk + 1) * P] : TOTE;

    if (tid < BW) rcnt[tid] = 0;
    __syncthreads();
    for (int i = bb + tid; i < be; i += 256)
        atomicAdd(&rcnt[seg[i] & 63u], 1);
    __syncthreads();

    if (tid < BW) {          // threads 0..63 = wave 0 exactly
        const int v = rcnt[tid];
        int inc = v;
#pragma unroll
        for (int o = 1; o < 64; o <<= 1) {
            const int t = __shfl_up(inc, o);
            if (tid >= o) inc += t;
        }
        const int excl = inc - v;
        rcur[tid] = excl;
        const int h    = blk / BPH;
        const int base = (blk - h * BPH) * BW;
        if (base + tid < Nn) rowoff[h * Nn + base + tid] = bb + excl;
    }
    __syncthreads();

    for (int i = bb + tid; i < be; i += 256) {
        const unsigned pk = seg[i];
        const int pos = atomicAdd(&rcur[pk & 63u], 1);
        seg2[bb + pos] = (unsigned short)(pk >> 6);
    }
}

// ---------------------------------------------------------------------------
// Accum: one 8-lane group (float4 channels) per destination row. Register
// accumulation, zero LDS, zero atomics. Depth-2 pipelined xl gathers.
// ---------------------------------------------------------------------------
__global__ __launch_bounds__(256, 4)
void accum_kernel(const int* __restrict__ rowoff, const unsigned short* __restrict__ seg2,
                  const float* __restrict__ xl, const float* __restrict__ xr,
                  const float* __restrict__ att, const float* __restrict__ bias,
                  float* __restrict__ out) {
    const int tid = threadIdx.x;
    const int l8  = tid & 7;
    const int r   = blockIdx.x * 32 + (tid >> 3);   // NR = 6250*32 exactly
    const int h   = r / Nn;
    const int n   = r - h * Nn;

    const float4* xl4 = (const float4*)xl;
    const float4  xr4 = ((const float4*)xr)[(size_t)r * 8 + l8];
    const float4  a4  = ((const float4*)att)[h * 8 + l8];

    const int beg = rowoff[r];
    const int end = (r + 1 < NR) ? rowoff[r + 1] : TOTE;

    // self-loop
    const float4 xs = xl4[(size_t)r * 8 + l8];
    float4 acc;
    float  den;
    {
        float4 hv;
        hv.x = xs.x + xr4.x; hv.y = xs.y + xr4.y; hv.z = xs.z + xr4.z; hv.w = xs.w + xr4.w;
        float4 lv;
        lv.x = fmaxf(hv.x, 0.f) + NEG_SLOPE * fminf(hv.x, 0.f);
        lv.y = fmaxf(hv.y, 0.f) + NEG_SLOPE * fminf(hv.y, 0.f);
        lv.z = fmaxf(hv.z, 0.f) + NEG_SLOPE * fminf(hv.z, 0.f);
        lv.w = fmaxf(hv.w, 0.f) + NEG_SLOPE * fminf(hv.w, 0.f);
        float p = lv.x * a4.x + lv.y * a4.y + lv.z * a4.z + lv.w * a4.w;
        p += __shfl_xor(p, 1);
        p += __shfl_xor(p, 2);
        p += __shfl_xor(p, 4);
        const float w = __expf(p);
        acc.x = w * xs.x; acc.y = w * xs.y; acc.z = w * xs.z; acc.w = w * xs.w;
        den   = w;
    }

    for (int j = beg; j < end; j += 8) {
        const int rem = end - j;
        const int m   = rem < 8 ? rem : 8;
        const int idx = j + l8;
        const int sv  = (idx < end) ? (int)seg2[idx] : 0;

        int    s  = __shfl(sv, 0, 8);
        float4 xg = xl4[((size_t)h * Nn + s) * 8 + l8];
        for (int k = 0; k < m; ++k) {
            const int    k2 = (k + 1 < m) ? k + 1 : k;
            const int    s2 = __shfl(sv, k2, 8);
            const float4 xn = xl4[((size_t)h * Nn + s2) * 8 + l8];   // prefetch

            float4 hv;
            hv.x = xg.x + xr4.x; hv.y = xg.y + xr4.y; hv.z = xg.z + xr4.z; hv.w = xg.w + xr4.w;
            float4 lv;
            lv.x = fmaxf(hv.x, 0.f) + NEG_SLOPE * fminf(hv.x, 0.f);
            lv.y = fmaxf(hv.y, 0.f) + NEG_SLOPE * fminf(hv.y, 0.f);
            lv.z = fmaxf(hv.z, 0.f) + NEG_SLOPE * fminf(hv.z, 0.f);
            lv.w = fmaxf(hv.w, 0.f) + NEG_SLOPE * fminf(hv.w, 0.f);
            float p = lv.x * a4.x + lv.y * a4.y + lv.z * a4.z + lv.w * a4.w;
            p += __shfl_xor(p, 1);
            p += __shfl_xor(p, 2);
            p += __shfl_xor(p, 4);
            const float w = __expf(p);
            acc.x = fmaf(w, xg.x, acc.x);
            acc.y = fmaf(w, xg.y, acc.y);
            acc.z = fmaf(w, xg.z, acc.z);
            acc.w = fmaf(w, xg.w, acc.w);
            den += w;
            xg = xn;
        }
    }

    const float4 b4 = ((const float4*)bias)[h * 8 + l8];
    const float inv = 1.f / den;
    float4 o4;
    o4.x = acc.x * inv + b4.x;
    o4.y = acc.y * inv + b4.y;
    o4.z = acc.z * inv + b4.z;
    o4.w = acc.w * inv + b4.w;
    ((float4*)out)[(size_t)n * 32 + h * 8 + l8] = o4;   // out[n][h*32 + l8*4 ..]
}

extern "C" void kernel_launch(void* const* d_in, const int* in_sizes, int n_in,
                              void* d_out, int out_size, void* d_ws, size_t ws_size,
                              hipStream_t stream) {
    const float* x    = (const float*)d_in[0];
    const int*   ei   = (const int*)d_in[1];
    const float* Wl   = (const float*)d_in[2];
    const float* Wr   = (const float*)d_in[3];
    const float* att  = (const float*)d_in[4];
    const float* bias = (const float*)d_in[5];
    float* out = (float*)d_out;

    // workspace: xl[6.4M f] | xr[6.4M f] | seg[6.4M u32] | bcnt/boff/bcur[NBP]
    //            | bsum[SB] | rowoff[NR] | seg2[6.4M u16]
    float*    xl     = (float*)d_ws;
    float*    xr     = xl + (size_t)Hh * Nn * D;
    unsigned* seg    = (unsigned*)(xr + (size_t)Hh * Nn * D);
    int*      bcnt   = (int*)(seg + (size_t)TOTE);
    int*      boff   = bcnt + NBP;
    int*      bcur   = boff + NBP;
    int*      bsum   = bcur + NBP;
    int*      rowoff = bsum + 64;
    unsigned short* seg2 = (unsigned short*)(rowoff + NR);

    hipMemsetAsync(bcnt, 0, NBP * sizeof(int), stream);

    dim3 gT((Nn + 7) / 8, Hh);
    transform_kernel<<<gT, 256, 0, stream>>>(x, Wl, Wr, xl, xr);

    dim3 gE((Ee + 255) / 256, Hh);
    bhist_kernel<<<gE, 256, 0, stream>>>(ei, bcnt);

    scan1_kernel<<<SB, 1024, 0, stream>>>(bcnt, bsum);
    scan2_kernel<<<1, 64, 0, stream>>>(bsum);
    scan3_kernel<<<SB, 1024, 0, stream>>>(bcnt, bsum, boff, bcur);

    bscatter_kernel<<<gE, 256, 0, stream>>>(ei, bcur, seg);

    rowsort_kernel<<<NB, 256, 0, stream>>>(boff, seg, seg2, rowoff);

    accum_kernel<<<NR / 32, 256, 0, stream>>>(rowoff, seg2, xl, xr, att, bias, out);
}

// Round 6
// 355.080 us; speedup vs baseline: 9.6280x; 2.5640x over previous
//
#include <hip/hip_runtime.h>

#define NEG_SLOPE 0.2f

static constexpr int Hh   = 4;
static constexpr int Nn   = 50000;
static constexpr int Ee   = 1600000;
static constexpr int D    = 32;
static constexpr int NR   = Hh * Nn;                  // 200000 rows
static constexpr int TOTE = Hh * Ee;                  // 6.4M edges

static constexpr int GBITS = 9;                       // 512 nodes per coarse bin
static constexpr int GW    = 1 << GBITS;
static constexpr int BPH   = (Nn + GW - 1) / GW;      // 98 bins/head
static constexpr int NBIN  = Hh * BPH;                // 392 bins
static constexpr int CAP   = 18432;                   // mean 16384 + 16 sigma
static constexpr int T1    = 8192;                    // partition tile (edges)
static constexpr int TPB1  = 512;
static constexpr int EPT   = T1 / TPB1;               // 16 edges/thread

// ---------------------------------------------------------------------------
// xl = x @ W_l, xr = x @ W_r per head. 8 nodes x 32 ch per block.
// ---------------------------------------------------------------------------
__global__ void transform_kernel(const float* __restrict__ x,
                                 const float* __restrict__ Wl,
                                 const float* __restrict__ Wr,
                                 float* __restrict__ xl,
                                 float* __restrict__ xr) {
    __shared__ float wl_s[D * D];
    __shared__ float wr_s[D * D];
    const int h   = blockIdx.y;
    const int tid = threadIdx.x;
    for (int i = tid; i < D * D; i += 256) {
        wl_s[i] = Wl[h * D * D + i];
        wr_s[i] = Wr[h * D * D + i];
    }
    __syncthreads();

    const int node = blockIdx.x * 8 + (tid >> 5);
    const int c    = tid & 31;
    if (node >= Nn) return;

    const float* xrow = x + ((size_t)h * Nn + node) * D;
    float al = 0.f, ar = 0.f;
#pragma unroll
    for (int k = 0; k < D; ++k) {
        const float xv = xrow[k];
        al = fmaf(xv, wl_s[k * D + c], al);
        ar = fmaf(xv, wr_s[k * D + c], ar);
    }
    const size_t o = ((size_t)h * Nn + node) * D + c;
    xl[o] = al;
    xr[o] = ar;
}

// ---------------------------------------------------------------------------
// Pass 1: LDS-staged radix partition of edges into 392 coarse bins.
// Entry = (src<<16)|dst. Per tile: LDS hist -> scan -> rank -> reorder in LDS
// -> one global atomicAdd per (block,bin) -> coalesced run copy-out.
// ---------------------------------------------------------------------------
__global__ __launch_bounds__(TPB1)
void partition_kernel(const int* __restrict__ ei, int* __restrict__ bincur,
                      unsigned* __restrict__ seg1) {
    __shared__ unsigned stage[T1];
    __shared__ unsigned char binid[T1];
    __shared__ int hcnt[BPH];
    __shared__ int lstart[BPH];
    __shared__ int lcur[BPH];
    __shared__ int gdst[BPH];
    __shared__ int hs[128];

    const int h   = blockIdx.y;
    const int tb  = blockIdx.x * T1;
    const int tid = threadIdx.x;

    for (int i = tid; i < BPH; i += TPB1) hcnt[i] = 0;
    __syncthreads();

    unsigned ent[EPT];
#pragma unroll
    for (int k = 0; k < EPT; ++k) {
        const int e = tb + k * TPB1 + tid;
        if (e < Ee) {
            const int src = ei[(size_t)h * 2 * Ee + e];
            const int dst = ei[(size_t)h * 2 * Ee + Ee + e];
            ent[k] = ((unsigned)src << 16) | (unsigned)dst;
            atomicAdd(&hcnt[dst >> GBITS], 1);
        } else {
            ent[k] = 0xffffffffu;
        }
    }
    __syncthreads();

    // inclusive H-S scan of 98 bin counts (threads 0..127)
    if (tid < 128) hs[tid] = (tid < BPH) ? hcnt[tid] : 0;
    __syncthreads();
    for (int o = 1; o < 128; o <<= 1) {
        int v = 0;
        if (tid < 128 && tid >= o) v = hs[tid - o];
        __syncthreads();
        if (tid < 128) hs[tid] += v;
        __syncthreads();
    }
    if (tid < BPH) {
        const int ex = hs[tid] - hcnt[tid];
        lstart[tid] = ex;
        lcur[tid]   = ex;
        if (hcnt[tid] > 0) {
            const int g = atomicAdd(&bincur[h * BPH + tid], hcnt[tid]);
            gdst[tid] = (h * BPH + tid) * CAP + g;
        }
    }
    __syncthreads();

    // rank + reorder into LDS stage
#pragma unroll
    for (int k = 0; k < EPT; ++k) {
        if (ent[k] != 0xffffffffu) {
            const int b = (int)((ent[k] & 0xffffu) >> GBITS);
            const int p = atomicAdd(&lcur[b], 1);
            stage[p] = ent[k];
        }
    }
    __syncthreads();

    // fill position->bin map
    if (tid < BPH) {
        const int s = lstart[tid];
        const int c = hcnt[tid];
        for (int i = 0; i < c; ++i) binid[s + i] = (unsigned char)tid;
    }
    __syncthreads();

    const int tot = lstart[BPH - 1] + hcnt[BPH - 1];
    for (int i = tid; i < tot; i += TPB1) {
        const int b = binid[i];
        seg1[(size_t)gdst[b] + (i - lstart[b])] = stage[i];
    }
}

// ---------------------------------------------------------------------------
// Exclusive scan of 392 bin counts -> compact global bases. Sets rowoff[NR].
// ---------------------------------------------------------------------------
__global__ void binscan_kernel(const int* __restrict__ bincur, int* __restrict__ gbase,
                               int* __restrict__ rowoff) {
    __shared__ int s[512];
    const int tid = threadIdx.x;
    const int v = (tid < NBIN) ? bincur[tid] : 0;
    s[tid] = v;
    __syncthreads();
    for (int o = 1; o < 512; o <<= 1) {
        const int a = (tid >= o) ? s[tid - o] : 0;
        __syncthreads();
        s[tid] += a;
        __syncthreads();
    }
    if (tid < NBIN) gbase[tid] = s[tid] - v;
    if (tid == NBIN - 1) rowoff[NR] = s[tid];   // = TOTE
}

// ---------------------------------------------------------------------------
// Pass 2: per-bin row sort. One block per bin: 512-row LDS hist + scan,
// scatter src (u16) into the bin's compact ~33KB window; emit rowoff.
// ---------------------------------------------------------------------------
__global__ __launch_bounds__(256)
void rowsort_kernel(const int* __restrict__ bincur, const int* __restrict__ gbase,
                    const unsigned* __restrict__ seg1,
                    unsigned short* __restrict__ seg2, int* __restrict__ rowoff) {
    __shared__ int rcnt[GW];
    __shared__ int rcur[GW];
    const int bin = blockIdx.x;
    const int h   = bin / BPH;
    const int b   = bin - h * BPH;
    const int nodebase = b * GW;
    const int nrows = (Nn - nodebase) < GW ? (Nn - nodebase) : GW;
    const int cnt  = bincur[bin];
    const int gb   = gbase[bin];
    const size_t base = (size_t)bin * CAP;
    const int tid = threadIdx.x;

    rcnt[tid] = 0; rcnt[tid + 256] = 0;
    __syncthreads();
    for (int i = tid; i < cnt; i += 256)
        atomicAdd(&rcnt[(int)(seg1[base + i] & 0xffffu) - nodebase], 1);
    __syncthreads();

    // inclusive H-S scan over 512 with 256 threads
    const int c0 = rcnt[tid], c1 = rcnt[tid + 256];
    for (int o = 1; o < GW; o <<= 1) {
        const int a0 = (tid >= o) ? rcnt[tid - o] : 0;
        const int a1 = (tid + 256 >= o) ? rcnt[tid + 256 - o] : 0;
        __syncthreads();
        rcnt[tid] += a0; rcnt[tid + 256] += a1;
        __syncthreads();
    }
    const int e0 = rcnt[tid] - c0;
    const int e1 = rcnt[tid + 256] - c1;
    rcur[tid] = e0; rcur[tid + 256] = e1;
    if (tid < nrows)       rowoff[h * Nn + nodebase + tid]       = gb + e0;
    if (tid + 256 < nrows) rowoff[h * Nn + nodebase + tid + 256] = gb + e1;
    __syncthreads();

    for (int i = tid; i < cnt; i += 256) {
        const unsigned ent = seg1[base + i];
        const int row = (int)(ent & 0xffffu) - nodebase;
        const int p = atomicAdd(&rcur[row], 1);
        seg2[(size_t)gb + p] = (unsigned short)(ent >> 16);
    }
}

// ---------------------------------------------------------------------------
// Accum: one 8-lane group (float4 channels) per destination row. Register
// accumulation, zero LDS, zero atomics. Depth-2 pipelined xl gathers.
// ---------------------------------------------------------------------------
__global__ __launch_bounds__(256, 4)
void accum_kernel(const int* __restrict__ rowoff, const unsigned short* __restrict__ seg2,
                  const float* __restrict__ xl, const float* __restrict__ xr,
                  const float* __restrict__ att, const float* __restrict__ bias,
                  float* __restrict__ out) {
    const int tid = threadIdx.x;
    const int l8  = tid & 7;
    const int r   = blockIdx.x * 32 + (tid >> 3);   // NR = 6250*32 exactly
    const int h   = r / Nn;
    const int n   = r - h * Nn;

    const float4* xl4 = (const float4*)xl;
    const float4  xr4 = ((const float4*)xr)[(size_t)r * 8 + l8];
    const float4  a4  = ((const float4*)att)[h * 8 + l8];

    const int beg = rowoff[r];
    const int end = rowoff[r + 1];

    // self-loop
    const float4 xs = xl4[(size_t)r * 8 + l8];
    float4 acc;
    float  den;
    {
        float4 hv;
        hv.x = xs.x + xr4.x; hv.y = xs.y + xr4.y; hv.z = xs.z + xr4.z; hv.w = xs.w + xr4.w;
        float4 lv;
        lv.x = fmaxf(hv.x, 0.f) + NEG_SLOPE * fminf(hv.x, 0.f);
        lv.y = fmaxf(hv.y, 0.f) + NEG_SLOPE * fminf(hv.y, 0.f);
        lv.z = fmaxf(hv.z, 0.f) + NEG_SLOPE * fminf(hv.z, 0.f);
        lv.w = fmaxf(hv.w, 0.f) + NEG_SLOPE * fminf(hv.w, 0.f);
        float p = lv.x * a4.x + lv.y * a4.y + lv.z * a4.z + lv.w * a4.w;
        p += __shfl_xor(p, 1);
        p += __shfl_xor(p, 2);
        p += __shfl_xor(p, 4);
        const float w = __expf(p);
        acc.x = w * xs.x; acc.y = w * xs.y; acc.z = w * xs.z; acc.w = w * xs.w;
        den   = w;
    }

    for (int j = beg; j < end; j += 8) {
        const int rem = end - j;
        const int m   = rem < 8 ? rem : 8;
        const int idx = j + l8;
        const int sv  = (idx < end) ? (int)seg2[idx] : 0;

        int    s  = __shfl(sv, 0, 8);
        float4 xg = xl4[((size_t)h * Nn + s) * 8 + l8];
        for (int k = 0; k < m; ++k) {
            const int    k2 = (k + 1 < m) ? k + 1 : k;
            const int    s2 = __shfl(sv, k2, 8);
            const float4 xn = xl4[((size_t)h * Nn + s2) * 8 + l8];   // prefetch

            float4 hv;
            hv.x = xg.x + xr4.x; hv.y = xg.y + xr4.y; hv.z = xg.z + xr4.z; hv.w = xg.w + xr4.w;
            float4 lv;
            lv.x = fmaxf(hv.x, 0.f) + NEG_SLOPE * fminf(hv.x, 0.f);
            lv.y = fmaxf(hv.y, 0.f) + NEG_SLOPE * fminf(hv.y, 0.f);
            lv.z = fmaxf(hv.z, 0.f) + NEG_SLOPE * fminf(hv.z, 0.f);
            lv.w = fmaxf(hv.w, 0.f) + NEG_SLOPE * fminf(hv.w, 0.f);
            float p = lv.x * a4.x + lv.y * a4.y + lv.z * a4.z + lv.w * a4.w;
            p += __shfl_xor(p, 1);
            p += __shfl_xor(p, 2);
            p += __shfl_xor(p, 4);
            const float w = __expf(p);
            acc.x = fmaf(w, xg.x, acc.x);
            acc.y = fmaf(w, xg.y, acc.y);
            acc.z = fmaf(w, xg.z, acc.z);
            acc.w = fmaf(w, xg.w, acc.w);
            den += w;
            xg = xn;
        }
    }

    const float4 b4 = ((const float4*)bias)[h * 8 + l8];
    const float inv = 1.f / den;
    float4 o4;
    o4.x = acc.x * inv + b4.x;
    o4.y = acc.y * inv + b4.y;
    o4.z = acc.z * inv + b4.z;
    o4.w = acc.w * inv + b4.w;
    ((float4*)out)[(size_t)n * 32 + h * 8 + l8] = o4;
}

extern "C" void kernel_launch(void* const* d_in, const int* in_sizes, int n_in,
                              void* d_out, int out_size, void* d_ws, size_t ws_size,
                              hipStream_t stream) {
    const float* x    = (const float*)d_in[0];
    const int*   ei   = (const int*)d_in[1];
    const float* Wl   = (const float*)d_in[2];
    const float* Wr   = (const float*)d_in[3];
    const float* att  = (const float*)d_in[4];
    const float* bias = (const float*)d_in[5];
    float* out = (float*)d_out;

    // workspace: xl[6.4M f] | xr[6.4M f] | seg1[392*18432 u32 = 28.9MB]
    //            | seg2[6.4M u16] | bincur[392] | gbase[392] | rowoff[NR+1]
    float*    xl     = (float*)d_ws;
    float*    xr     = xl + (size_t)Hh * Nn * D;
    unsigned* seg1   = (unsigned*)(xr + (size_t)Hh * Nn * D);
    unsigned short* seg2 = (unsigned short*)(seg1 + (size_t)NBIN * CAP);
    int*      bincur = (int*)(seg2 + (size_t)TOTE);
    int*      gbase  = bincur + NBIN;
    int*      rowoff = gbase + NBIN;

    hipMemsetAsync(bincur, 0, NBIN * sizeof(int), stream);

    dim3 gT((Nn + 7) / 8, Hh);
    transform_kernel<<<gT, 256, 0, stream>>>(x, Wl, Wr, xl, xr);

    dim3 gP((Ee + T1 - 1) / T1, Hh);
    partition_kernel<<<gP, TPB1, 0, stream>>>(ei, bincur, seg1);

    binscan_kernel<<<1, 512, 0, stream>>>(bincur, gbase, rowoff);

    rowsort_kernel<<<NBIN, 256, 0, stream>>>(bincur, gbase, seg1, seg2, rowoff);

    accum_kernel<<<NR / 32, 256, 0, stream>>>(rowoff, seg2, xl, xr, att, bias, out);
}

// Round 7
// 322.793 us; speedup vs baseline: 10.5911x; 1.1000x over previous
//
#include <hip/hip_runtime.h>

#define NEG_SLOPE 0.2f

static constexpr int Hh   = 4;
static constexpr int Nn   = 50000;
static constexpr int Ee   = 1600000;
static constexpr int D    = 32;
static constexpr int NR   = Hh * Nn;                  // 200000 rows
static constexpr int TOTE = Hh * Ee;                  // 6.4M edges

static constexpr int GBITS = 9;                       // 512 nodes per coarse bin
static constexpr int GW    = 1 << GBITS;
static constexpr int BPH   = (Nn + GW - 1) / GW;      // 98 bins/head
static constexpr int NBIN  = Hh * BPH;                // 392 bins
static constexpr int CAP   = 18432;                   // mean 16384 + 16 sigma
static constexpr int T1    = 8192;                    // partition tile (edges)
static constexpr int TPB1  = 512;
static constexpr int EPT   = T1 / TPB1;               // 16 edges/thread
static constexpr int BLKH  = 1563;                    // ceil(50000/32) blocks per head

// ---------------------------------------------------------------------------
// xl = x @ W_l, xr = x @ W_r per head. 8 nodes x 32 ch per block.
// ---------------------------------------------------------------------------
__global__ void transform_kernel(const float* __restrict__ x,
                                 const float* __restrict__ Wl,
                                 const float* __restrict__ Wr,
                                 float* __restrict__ xl,
                                 float* __restrict__ xr) {
    __shared__ float wl_s[D * D];
    __shared__ float wr_s[D * D];
    const int h   = blockIdx.y;
    const int tid = threadIdx.x;
    for (int i = tid; i < D * D; i += 256) {
        wl_s[i] = Wl[h * D * D + i];
        wr_s[i] = Wr[h * D * D + i];
    }
    __syncthreads();

    const int node = blockIdx.x * 8 + (tid >> 5);
    const int c    = tid & 31;
    if (node >= Nn) return;

    const float* xrow = x + ((size_t)h * Nn + node) * D;
    float al = 0.f, ar = 0.f;
#pragma unroll
    for (int k = 0; k < D; ++k) {
        const float xv = xrow[k];
        al = fmaf(xv, wl_s[k * D + c], al);
        ar = fmaf(xv, wr_s[k * D + c], ar);
    }
    const size_t o = ((size_t)h * Nn + node) * D + c;
    xl[o] = al;
    xr[o] = ar;
}

// ---------------------------------------------------------------------------
// Pass 1: LDS-staged radix partition into 392 coarse bins. Entry=(src<<16)|dst.
// int4 ei loads; bin derived from entry during copy-out (no binid array).
// ---------------------------------------------------------------------------
__global__ __launch_bounds__(TPB1)
void partition_kernel(const int* __restrict__ ei, int* __restrict__ bincur,
                      unsigned* __restrict__ seg1) {
    __shared__ unsigned stage[T1];
    __shared__ int hcnt[BPH];
    __shared__ int lstart[BPH];
    __shared__ int lcur[BPH];
    __shared__ int gdst[BPH];
    __shared__ int hs[128];

    const int h   = blockIdx.y;
    const int tb  = blockIdx.x * T1;
    const int tid = threadIdx.x;

    for (int i = tid; i < BPH; i += TPB1) hcnt[i] = 0;
    __syncthreads();

    const int4* srcp = (const int4*)(ei + (size_t)h * 2 * Ee);
    const int4* dstp = (const int4*)(ei + (size_t)h * 2 * Ee + Ee);

    unsigned ent[EPT];
#pragma unroll
    for (int k = 0; k < EPT / 4; ++k) {
        const int e4 = tb + 4 * (k * TPB1 + tid);    // Ee % 4 == 0
        if (e4 < Ee) {
            const int4 s4 = srcp[e4 >> 2];
            const int4 d4 = dstp[e4 >> 2];
            ent[4 * k + 0] = ((unsigned)s4.x << 16) | (unsigned)d4.x;
            ent[4 * k + 1] = ((unsigned)s4.y << 16) | (unsigned)d4.y;
            ent[4 * k + 2] = ((unsigned)s4.z << 16) | (unsigned)d4.z;
            ent[4 * k + 3] = ((unsigned)s4.w << 16) | (unsigned)d4.w;
            atomicAdd(&hcnt[d4.x >> GBITS], 1);
            atomicAdd(&hcnt[d4.y >> GBITS], 1);
            atomicAdd(&hcnt[d4.z >> GBITS], 1);
            atomicAdd(&hcnt[d4.w >> GBITS], 1);
        } else {
            ent[4 * k + 0] = ent[4 * k + 1] = ent[4 * k + 2] = ent[4 * k + 3] = 0xffffffffu;
        }
    }
    __syncthreads();

    // inclusive H-S scan of 98 bin counts (threads 0..127)
    if (tid < 128) hs[tid] = (tid < BPH) ? hcnt[tid] : 0;
    __syncthreads();
    for (int o = 1; o < 128; o <<= 1) {
        int v = 0;
        if (tid < 128 && tid >= o) v = hs[tid - o];
        __syncthreads();
        if (tid < 128) hs[tid] += v;
        __syncthreads();
    }
    if (tid < BPH) {
        const int ex = hs[tid] - hcnt[tid];
        lstart[tid] = ex;
        lcur[tid]   = ex;
        if (hcnt[tid] > 0) {
            const int g = atomicAdd(&bincur[h * BPH + tid], hcnt[tid]);
            gdst[tid] = (h * BPH + tid) * CAP + g;
        }
    }
    __syncthreads();

    // rank + reorder into LDS stage
#pragma unroll
    for (int k = 0; k < EPT; ++k) {
        if (ent[k] != 0xffffffffu) {
            const int b = (int)((ent[k] & 0xffffu) >> GBITS);
            const int p = atomicAdd(&lcur[b], 1);
            stage[p] = ent[k];
        }
    }
    __syncthreads();

    const int tot = lstart[BPH - 1] + hcnt[BPH - 1];
    for (int i = tid; i < tot; i += TPB1) {
        const unsigned e = stage[i];
        const int b = (int)((e & 0xffffu) >> GBITS);
        seg1[(size_t)gdst[b] + (i - lstart[b])] = e;
    }
}

// ---------------------------------------------------------------------------
// Exclusive scan of 392 bin counts -> compact global bases. Sets rowoff[NR].
// ---------------------------------------------------------------------------
__global__ void binscan_kernel(const int* __restrict__ bincur, int* __restrict__ gbase,
                               int* __restrict__ rowoff) {
    __shared__ int s[512];
    const int tid = threadIdx.x;
    const int v = (tid < NBIN) ? bincur[tid] : 0;
    s[tid] = v;
    __syncthreads();
    for (int o = 1; o < 512; o <<= 1) {
        const int a = (tid >= o) ? s[tid - o] : 0;
        __syncthreads();
        s[tid] += a;
        __syncthreads();
    }
    if (tid < NBIN) gbase[tid] = s[tid] - v;
    if (tid == NBIN - 1) rowoff[NR] = s[tid];   // = TOTE
}

// ---------------------------------------------------------------------------
// Pass 2: per-bin row sort, 512 threads. 512-row LDS hist + scan, scatter src
// (u16) into the bin's compact window; emit rowoff.
// ---------------------------------------------------------------------------
__global__ __launch_bounds__(512)
void rowsort_kernel(const int* __restrict__ bincur, const int* __restrict__ gbase,
                    const unsigned* __restrict__ seg1,
                    unsigned short* __restrict__ seg2, int* __restrict__ rowoff) {
    __shared__ int rcnt[GW];
    __shared__ int rcur[GW];
    const int bin = blockIdx.x;
    const int h   = bin / BPH;
    const int b   = bin - h * BPH;
    const int nodebase = b * GW;
    const int nrows = (Nn - nodebase) < GW ? (Nn - nodebase) : GW;
    const int cnt  = bincur[bin];
    const int gb   = gbase[bin];
    const size_t base = (size_t)bin * CAP;
    const int tid = threadIdx.x;

    rcnt[tid] = 0;
    __syncthreads();
    for (int i = tid; i < cnt; i += 512)
        atomicAdd(&rcnt[(int)(seg1[base + i] & 0xffffu) - nodebase], 1);
    __syncthreads();

    // inclusive H-S scan in place (512 threads, one per counter)
    const int v = rcnt[tid];
    for (int o = 1; o < GW; o <<= 1) {
        const int a = (tid >= o) ? rcnt[tid - o] : 0;
        __syncthreads();
        rcnt[tid] += a;
        __syncthreads();
    }
    const int excl = rcnt[tid] - v;
    rcur[tid] = excl;
    if (tid < nrows) rowoff[h * Nn + nodebase + tid] = gb + excl;
    __syncthreads();

    for (int i = tid; i < cnt; i += 512) {
        const unsigned ent = seg1[base + i];
        const int row = (int)(ent & 0xffffu) - nodebase;
        const int p = atomicAdd(&rcur[row], 1);
        seg2[(size_t)gb + p] = (unsigned short)(ent >> 16);
    }
}

// ---------------------------------------------------------------------------
// Accum: one 8-lane group (float4 channels) per destination row. Register
// accumulation, zero LDS/atomics. XCD-pair-per-head swizzle: launch idx L ->
// xcd = L&7 (dispatch round-robin heuristic), head = xcd>>1, so each XCD's L2
// only caches one head's 6.4MB xl slice.
// ---------------------------------------------------------------------------
__global__ __launch_bounds__(256, 4)
void accum_kernel(const int* __restrict__ rowoff, const unsigned short* __restrict__ seg2,
                  const float* __restrict__ xl, const float* __restrict__ xr,
                  const float* __restrict__ att, const float* __restrict__ bias,
                  float* __restrict__ out) {
    const int tid  = threadIdx.x;
    const int l8   = tid & 7;
    const int L    = blockIdx.x;
    const int xcd  = L & 7;
    const int h    = xcd >> 1;
    const int ib   = ((L >> 3) << 1) | (xcd & 1);    // block index within head
    if (ib >= BLKH) return;
    const int n    = ib * 32 + (tid >> 3);
    if (n >= Nn) return;
    const int r    = h * Nn + n;

    const float4* xl4 = (const float4*)xl;
    const float4  xr4 = ((const float4*)xr)[(size_t)r * 8 + l8];
    const float4  a4  = ((const float4*)att)[h * 8 + l8];

    const int beg = rowoff[r];
    const int end = rowoff[r + 1];

    // self-loop
    const float4 xs = xl4[(size_t)r * 8 + l8];
    float4 acc;
    float  den;
    {
        float4 hv;
        hv.x = xs.x + xr4.x; hv.y = xs.y + xr4.y; hv.z = xs.z + xr4.z; hv.w = xs.w + xr4.w;
        float4 lv;
        lv.x = fmaxf(hv.x, 0.f) + NEG_SLOPE * fminf(hv.x, 0.f);
        lv.y = fmaxf(hv.y, 0.f) + NEG_SLOPE * fminf(hv.y, 0.f);
        lv.z = fmaxf(hv.z, 0.f) + NEG_SLOPE * fminf(hv.z, 0.f);
        lv.w = fmaxf(hv.w, 0.f) + NEG_SLOPE * fminf(hv.w, 0.f);
        float p = lv.x * a4.x + lv.y * a4.y + lv.z * a4.z + lv.w * a4.w;
        p += __shfl_xor(p, 1);
        p += __shfl_xor(p, 2);
        p += __shfl_xor(p, 4);
        const float w = __expf(p);
        acc.x = w * xs.x; acc.y = w * xs.y; acc.z = w * xs.z; acc.w = w * xs.w;
        den   = w;
    }

    for (int j = beg; j < end; j += 8) {
        const int rem = end - j;
        const int m   = rem < 8 ? rem : 8;
        const int idx = j + l8;
        const int sv  = (idx < end) ? (int)seg2[idx] : 0;

        int    s  = __shfl(sv, 0, 8);
        float4 xg = xl4[((size_t)h * Nn + s) * 8 + l8];
        for (int k = 0; k < m; ++k) {
            const int    k2 = (k + 1 < m) ? k + 1 : k;
            const int    s2 = __shfl(sv, k2, 8);
            const float4 xn = xl4[((size_t)h * Nn + s2) * 8 + l8];   // prefetch

            float4 hv;
            hv.x = xg.x + xr4.x; hv.y = xg.y + xr4.y; hv.z = xg.z + xr4.z; hv.w = xg.w + xr4.w;
            float4 lv;
            lv.x = fmaxf(hv.x, 0.f) + NEG_SLOPE * fminf(hv.x, 0.f);
            lv.y = fmaxf(hv.y, 0.f) + NEG_SLOPE * fminf(hv.y, 0.f);
            lv.z = fmaxf(hv.z, 0.f) + NEG_SLOPE * fminf(hv.z, 0.f);
            lv.w = fmaxf(hv.w, 0.f) + NEG_SLOPE * fminf(hv.w, 0.f);
            float p = lv.x * a4.x + lv.y * a4.y + lv.z * a4.z + lv.w * a4.w;
            p += __shfl_xor(p, 1);
            p += __shfl_xor(p, 2);
            p += __shfl_xor(p, 4);
            const float w = __expf(p);
            acc.x = fmaf(w, xg.x, acc.x);
            acc.y = fmaf(w, xg.y, acc.y);
            acc.z = fmaf(w, xg.z, acc.z);
            acc.w = fmaf(w, xg.w, acc.w);
            den += w;
            xg = xn;
        }
    }

    const float4 b4 = ((const float4*)bias)[h * 8 + l8];
    const float inv = 1.f / den;
    float4 o4;
    o4.x = acc.x * inv + b4.x;
    o4.y = acc.y * inv + b4.y;
    o4.z = acc.z * inv + b4.z;
    o4.w = acc.w * inv + b4.w;
    ((float4*)out)[(size_t)n * 32 + h * 8 + l8] = o4;
}

extern "C" void kernel_launch(void* const* d_in, const int* in_sizes, int n_in,
                              void* d_out, int out_size, void* d_ws, size_t ws_size,
                              hipStream_t stream) {
    const float* x    = (const float*)d_in[0];
    const int*   ei   = (const int*)d_in[1];
    const float* Wl   = (const float*)d_in[2];
    const float* Wr   = (const float*)d_in[3];
    const float* att  = (const float*)d_in[4];
    const float* bias = (const float*)d_in[5];
    float* out = (float*)d_out;

    // workspace: xl[6.4M f] | xr[6.4M f] | seg1[392*18432 u32 = 28.9MB]
    //            | seg2[6.4M u16] | bincur[392] | gbase[392] | rowoff[NR+1]
    float*    xl     = (float*)d_ws;
    float*    xr     = xl + (size_t)Hh * Nn * D;
    unsigned* seg1   = (unsigned*)(xr + (size_t)Hh * Nn * D);
    unsigned short* seg2 = (unsigned short*)(seg1 + (size_t)NBIN * CAP);
    int*      bincur = (int*)(seg2 + (size_t)TOTE);
    int*      gbase  = bincur + NBIN;
    int*      rowoff = gbase + NBIN;

    hipMemsetAsync(bincur, 0, NBIN * sizeof(int), stream);

    dim3 gT((Nn + 7) / 8, Hh);
    transform_kernel<<<gT, 256, 0, stream>>>(x, Wl, Wr, xl, xr);

    dim3 gP((Ee + T1 - 1) / T1, Hh);
    partition_kernel<<<gP, TPB1, 0, stream>>>(ei, bincur, seg1);

    binscan_kernel<<<1, 512, 0, stream>>>(bincur, gbase, rowoff);

    rowsort_kernel<<<NBIN, 512, 0, stream>>>(bincur, gbase, seg1, seg2, rowoff);

    accum_kernel<<<8 * 782, 256, 0, stream>>>(rowoff, seg2, xl, xr, att, bias, out);
}

// Round 8
// 309.728 us; speedup vs baseline: 11.0378x; 1.0422x over previous
//
#include <hip/hip_runtime.h>

#define NEG_SLOPE 0.2f

static constexpr int Hh   = 4;
static constexpr int Nn   = 50000;
static constexpr int Ee   = 1600000;
static constexpr int D    = 32;
static constexpr int NR   = Hh * Nn;                  // 200000 rows
static constexpr int TOTE = Hh * Ee;                  // 6.4M edges

static constexpr int GBITS = 9;                       // 512 nodes per coarse bin
static constexpr int GW    = 1 << GBITS;
static constexpr int BPH   = (Nn + GW - 1) / GW;      // 98 bins/head
static constexpr int NBIN  = Hh * BPH;                // 392 bins
static constexpr int CAP   = 18432;                   // mean 16384 + 16 sigma
static constexpr int T1    = 8192;                    // partition tile (edges)
static constexpr int TPB1  = 512;
static constexpr int EPT   = T1 / TPB1;               // 16 edges/thread
static constexpr int BLKH  = 1563;                    // ceil(50000/32) blocks per head

// ---------------------------------------------------------------------------
// xl = x @ W_l, xr = x @ W_r per head. 8 nodes x 32 ch per block.
// ---------------------------------------------------------------------------
__global__ void transform_kernel(const float* __restrict__ x,
                                 const float* __restrict__ Wl,
                                 const float* __restrict__ Wr,
                                 float* __restrict__ xl,
                                 float* __restrict__ xr) {
    __shared__ float wl_s[D * D];
    __shared__ float wr_s[D * D];
    const int h   = blockIdx.y;
    const int tid = threadIdx.x;
    for (int i = tid; i < D * D; i += 256) {
        wl_s[i] = Wl[h * D * D + i];
        wr_s[i] = Wr[h * D * D + i];
    }
    __syncthreads();

    const int node = blockIdx.x * 8 + (tid >> 5);
    const int c    = tid & 31;
    if (node >= Nn) return;

    const float* xrow = x + ((size_t)h * Nn + node) * D;
    float al = 0.f, ar = 0.f;
#pragma unroll
    for (int k = 0; k < D; ++k) {
        const float xv = xrow[k];
        al = fmaf(xv, wl_s[k * D + c], al);
        ar = fmaf(xv, wr_s[k * D + c], ar);
    }
    const size_t o = ((size_t)h * Nn + node) * D + c;
    xl[o] = al;
    xr[o] = ar;
}

// ---------------------------------------------------------------------------
// Pass 1: LDS-staged radix partition into 392 coarse bins. Entry=(src<<16)|dst.
// Rank-first: ONE returning LDS-atomic pass gives in-block rank AND counts
// (no separate histogram pass). Then scan -> lstart, reserve global run,
// stage reorder in LDS, coalesced copy-out.
// ---------------------------------------------------------------------------
__global__ __launch_bounds__(TPB1)
void partition_kernel(const int* __restrict__ ei, int* __restrict__ bincur,
                      unsigned* __restrict__ seg1) {
    __shared__ unsigned stage[T1];
    __shared__ int lcur[BPH];      // counts after rank phase
    __shared__ int lstart[BPH];
    __shared__ int gdst[BPH];
    __shared__ int hs[128];

    const int h   = blockIdx.y;
    const int tb  = blockIdx.x * T1;
    const int tid = threadIdx.x;

    for (int i = tid; i < BPH; i += TPB1) lcur[i] = 0;
    __syncthreads();

    const int4* srcp = (const int4*)(ei + (size_t)h * 2 * Ee);
    const int4* dstp = (const int4*)(ei + (size_t)h * 2 * Ee + Ee);

    unsigned ent[EPT];
    unsigned short rk[EPT];
#pragma unroll
    for (int k = 0; k < EPT / 4; ++k) {
        const int e4 = tb + 4 * (k * TPB1 + tid);    // Ee % 4 == 0
        if (e4 < Ee) {
            const int4 s4 = srcp[e4 >> 2];
            const int4 d4 = dstp[e4 >> 2];
            ent[4 * k + 0] = ((unsigned)s4.x << 16) | (unsigned)d4.x;
            ent[4 * k + 1] = ((unsigned)s4.y << 16) | (unsigned)d4.y;
            ent[4 * k + 2] = ((unsigned)s4.z << 16) | (unsigned)d4.z;
            ent[4 * k + 3] = ((unsigned)s4.w << 16) | (unsigned)d4.w;
            rk[4 * k + 0] = (unsigned short)atomicAdd(&lcur[d4.x >> GBITS], 1);
            rk[4 * k + 1] = (unsigned short)atomicAdd(&lcur[d4.y >> GBITS], 1);
            rk[4 * k + 2] = (unsigned short)atomicAdd(&lcur[d4.z >> GBITS], 1);
            rk[4 * k + 3] = (unsigned short)atomicAdd(&lcur[d4.w >> GBITS], 1);
        } else {
            ent[4 * k + 0] = ent[4 * k + 1] = ent[4 * k + 2] = ent[4 * k + 3] = 0xffffffffu;
        }
    }
    __syncthreads();

    // inclusive H-S scan of 98 counts (threads 0..127)
    if (tid < 128) hs[tid] = (tid < BPH) ? lcur[tid] : 0;
    __syncthreads();
    for (int o = 1; o < 128; o <<= 1) {
        int v = 0;
        if (tid < 128 && tid >= o) v = hs[tid - o];
        __syncthreads();
        if (tid < 128) hs[tid] += v;
        __syncthreads();
    }
    if (tid < BPH) {
        lstart[tid] = hs[tid] - lcur[tid];
        if (lcur[tid] > 0) {
            const int g = atomicAdd(&bincur[h * BPH + tid], lcur[tid]);
            gdst[tid] = (h * BPH + tid) * CAP + g;
        }
    }
    __syncthreads();

    // reorder into LDS stage via saved rank
#pragma unroll
    for (int k = 0; k < EPT; ++k) {
        if (ent[k] != 0xffffffffu) {
            const int b = (int)((ent[k] & 0xffffu) >> GBITS);
            stage[lstart[b] + (int)rk[k]] = ent[k];
        }
    }
    __syncthreads();

    const int tot = lstart[BPH - 1] + lcur[BPH - 1];
    for (int i = tid; i < tot; i += TPB1) {
        const unsigned e = stage[i];
        const int b = (int)((e & 0xffffu) >> GBITS);
        seg1[(size_t)gdst[b] + (i - lstart[b])] = e;
    }
}

// ---------------------------------------------------------------------------
// Exclusive scan of 392 bin counts -> compact global bases. Sets rowoff[NR].
// ---------------------------------------------------------------------------
__global__ void binscan_kernel(const int* __restrict__ bincur, int* __restrict__ gbase,
                               int* __restrict__ rowoff) {
    __shared__ int s[512];
    const int tid = threadIdx.x;
    const int v = (tid < NBIN) ? bincur[tid] : 0;
    s[tid] = v;
    __syncthreads();
    for (int o = 1; o < 512; o <<= 1) {
        const int a = (tid >= o) ? s[tid - o] : 0;
        __syncthreads();
        s[tid] += a;
        __syncthreads();
    }
    if (tid < NBIN) gbase[tid] = s[tid] - v;
    if (tid == NBIN - 1) rowoff[NR] = s[tid];   // = TOTE
}

// ---------------------------------------------------------------------------
// Pass 2: per-bin row sort, 512 threads. 512-row LDS hist + scan, scatter src
// (u16) into the bin's compact window; emit rowoff.
// ---------------------------------------------------------------------------
__global__ __launch_bounds__(512)
void rowsort_kernel(const int* __restrict__ bincur, const int* __restrict__ gbase,
                    const unsigned* __restrict__ seg1,
                    unsigned short* __restrict__ seg2, int* __restrict__ rowoff) {
    __shared__ int rcnt[GW];
    __shared__ int rcur[GW];
    const int bin = blockIdx.x;
    const int h   = bin / BPH;
    const int b   = bin - h * BPH;
    const int nodebase = b * GW;
    const int nrows = (Nn - nodebase) < GW ? (Nn - nodebase) : GW;
    const int cnt  = bincur[bin];
    const int gb   = gbase[bin];
    const size_t base = (size_t)bin * CAP;
    const int tid = threadIdx.x;

    rcnt[tid] = 0;
    __syncthreads();
    for (int i = tid; i < cnt; i += 512)
        atomicAdd(&rcnt[(int)(seg1[base + i] & 0xffffu) - nodebase], 1);
    __syncthreads();

    // inclusive H-S scan in place (512 threads, one per counter)
    const int v = rcnt[tid];
    for (int o = 1; o < GW; o <<= 1) {
        const int a = (tid >= o) ? rcnt[tid - o] : 0;
        __syncthreads();
        rcnt[tid] += a;
        __syncthreads();
    }
    const int excl = rcnt[tid] - v;
    rcur[tid] = excl;
    if (tid < nrows) rowoff[h * Nn + nodebase + tid] = gb + excl;
    __syncthreads();

    for (int i = tid; i < cnt; i += 512) {
        const unsigned ent = seg1[base + i];
        const int row = (int)(ent & 0xffffu) - nodebase;
        const int p = atomicAdd(&rcur[row], 1);
        seg2[(size_t)gb + p] = (unsigned short)(ent >> 16);
    }
}

// ---------------------------------------------------------------------------
// Accum: one 8-lane group (float4 channels) per destination row. Register
// accumulation, zero LDS/atomics. Leaky = fmax(hv, 0.2*hv) (2 ops). Edge loop
// split into static-unroll full chunks + one tail. XCD-pair-per-head swizzle.
// ---------------------------------------------------------------------------
#define GAT_PROC(xg)                                                          \
    {                                                                         \
        float4 hv;                                                            \
        hv.x = (xg).x + xr4.x; hv.y = (xg).y + xr4.y;                         \
        hv.z = (xg).z + xr4.z; hv.w = (xg).w + xr4.w;                         \
        float4 lv;                                                            \
        lv.x = fmaxf(hv.x, NEG_SLOPE * hv.x);                                 \
        lv.y = fmaxf(hv.y, NEG_SLOPE * hv.y);                                 \
        lv.z = fmaxf(hv.z, NEG_SLOPE * hv.z);                                 \
        lv.w = fmaxf(hv.w, NEG_SLOPE * hv.w);                                 \
        float p = lv.x * a4.x + lv.y * a4.y + lv.z * a4.z + lv.w * a4.w;      \
        p += __shfl_xor(p, 1);                                                \
        p += __shfl_xor(p, 2);                                                \
        p += __shfl_xor(p, 4);                                                \
        const float w = __expf(p);                                            \
        acc.x = fmaf(w, (xg).x, acc.x);                                       \
        acc.y = fmaf(w, (xg).y, acc.y);                                       \
        acc.z = fmaf(w, (xg).z, acc.z);                                       \
        acc.w = fmaf(w, (xg).w, acc.w);                                       \
        den += w;                                                             \
    }

__global__ __launch_bounds__(256, 4)
void accum_kernel(const int* __restrict__ rowoff, const unsigned short* __restrict__ seg2,
                  const float* __restrict__ xl, const float* __restrict__ xr,
                  const float* __restrict__ att, const float* __restrict__ bias,
                  float* __restrict__ out) {
    const int tid  = threadIdx.x;
    const int l8   = tid & 7;
    const int L    = blockIdx.x;
    const int xcd  = L & 7;
    const int h    = xcd >> 1;
    const int ib   = ((L >> 3) << 1) | (xcd & 1);    // block index within head
    if (ib >= BLKH) return;
    const int n    = ib * 32 + (tid >> 3);
    if (n >= Nn) return;
    const int r    = h * Nn + n;

    const float4* xl4 = (const float4*)xl;
    const float4  xr4 = ((const float4*)xr)[(size_t)r * 8 + l8];
    const float4  a4  = ((const float4*)att)[h * 8 + l8];
    const int hbase = h * Nn;

    const int beg = rowoff[r];
    const int end = rowoff[r + 1];

    // self-loop
    const float4 xs = xl4[(size_t)r * 8 + l8];
    float4 acc = {0.f, 0.f, 0.f, 0.f};
    float  den = 0.f;
    GAT_PROC(xs);

    int j = beg;
    for (; j + 8 <= end; j += 8) {
        const int sv = (int)seg2[j + l8];
#pragma unroll
        for (int k = 0; k < 8; ++k) {
            const int    s  = __shfl(sv, k, 8);
            const float4 xg = xl4[((size_t)(hbase + s)) * 8 + l8];
            GAT_PROC(xg);
        }
    }
    if (j < end) {
        const int m = end - j;
        int idx = j + l8;
        if (idx >= end) idx = end - 1;
        const int sv = (int)seg2[idx];
        for (int k = 0; k < m; ++k) {
            const int    s  = __shfl(sv, k, 8);
            const float4 xg = xl4[((size_t)(hbase + s)) * 8 + l8];
            GAT_PROC(xg);
        }
    }

    const float4 b4 = ((const float4*)bias)[h * 8 + l8];
    const float inv = 1.f / den;
    float4 o4;
    o4.x = acc.x * inv + b4.x;
    o4.y = acc.y * inv + b4.y;
    o4.z = acc.z * inv + b4.z;
    o4.w = acc.w * inv + b4.w;
    ((float4*)out)[(size_t)n * 32 + h * 8 + l8] = o4;
}

extern "C" void kernel_launch(void* const* d_in, const int* in_sizes, int n_in,
                              void* d_out, int out_size, void* d_ws, size_t ws_size,
                              hipStream_t stream) {
    const float* x    = (const float*)d_in[0];
    const int*   ei   = (const int*)d_in[1];
    const float* Wl   = (const float*)d_in[2];
    const float* Wr   = (const float*)d_in[3];
    const float* att  = (const float*)d_in[4];
    const float* bias = (const float*)d_in[5];
    float* out = (float*)d_out;

    // workspace: xl[6.4M f] | xr[6.4M f] | seg1[392*18432 u32 = 28.9MB]
    //            | seg2[6.4M u16] | bincur[392] | gbase[392] | rowoff[NR+1]
    float*    xl     = (float*)d_ws;
    float*    xr     = xl + (size_t)Hh * Nn * D;
    unsigned* seg1   = (unsigned*)(xr + (size_t)Hh * Nn * D);
    unsigned short* seg2 = (unsigned short*)(seg1 + (size_t)NBIN * CAP);
    int*      bincur = (int*)(seg2 + (size_t)TOTE);
    int*      gbase  = bincur + NBIN;
    int*      rowoff = gbase + NBIN;

    hipMemsetAsync(bincur, 0, NBIN * sizeof(int), stream);

    dim3 gT((Nn + 7) / 8, Hh);
    transform_kernel<<<gT, 256, 0, stream>>>(x, Wl, Wr, xl, xr);

    dim3 gP((Ee + T1 - 1) / T1, Hh);
    partition_kernel<<<gP, TPB1, 0, stream>>>(ei, bincur, seg1);

    binscan_kernel<<<1, 512, 0, stream>>>(bincur, gbase, rowoff);

    rowsort_kernel<<<NBIN, 512, 0, stream>>>(bincur, gbase, seg1, seg2, rowoff);

    accum_kernel<<<8 * 782, 256, 0, stream>>>(rowoff, seg2, xl, xr, att, bias, out);
}

// Round 9
// 281.779 us; speedup vs baseline: 12.1326x; 1.0992x over previous
//
#include <hip/hip_runtime.h>

#define NEG_SLOPE 0.2f

static constexpr int Hh   = 4;
static constexpr int Nn   = 50000;
static constexpr int Ee   = 1600000;
static constexpr int D    = 32;
static constexpr int NR   = Hh * Nn;                  // 200000 rows
static constexpr int TOTE = Hh * Ee;                  // 6.4M edges

static constexpr int GBITS = 9;                       // 512 nodes per coarse bin
static constexpr int GW    = 1 << GBITS;
static constexpr int BPH   = (Nn + GW - 1) / GW;      // 98 bins/head
static constexpr int NBIN  = Hh * BPH;                // 392 bins
static constexpr int CAP   = 18432;                   // mean 16384 + 16 sigma
static constexpr int T1    = 8192;                    // partition tile (edges)
static constexpr int TPB1  = 512;
static constexpr int EPT   = T1 / TPB1;               // 16 edges/thread
static constexpr int BLKH  = 782;                     // ceil(50000/64) blocks/head

typedef _Float16 v2h __attribute__((ext_vector_type(2)));
struct H8 { v2h a, b, c, d; };                        // 8 halves = 16 B
union U16B { uint4 u; H8 h; };

#if defined(__has_builtin)
#if __has_builtin(__builtin_amdgcn_fdot2)
#define HAS_FDOT2 1
#endif
#endif

// ---------------------------------------------------------------------------
// xl = x @ W_l, xr = x @ W_r per head, stored as f16. 8 nodes x 32 ch / block.
// ---------------------------------------------------------------------------
__global__ void transform_kernel(const float* __restrict__ x,
                                 const float* __restrict__ Wl,
                                 const float* __restrict__ Wr,
                                 _Float16* __restrict__ xlh,
                                 _Float16* __restrict__ xrh) {
    __shared__ float wl_s[D * D];
    __shared__ float wr_s[D * D];
    const int h   = blockIdx.y;
    const int tid = threadIdx.x;
    for (int i = tid; i < D * D; i += 256) {
        wl_s[i] = Wl[h * D * D + i];
        wr_s[i] = Wr[h * D * D + i];
    }
    __syncthreads();

    const int node = blockIdx.x * 8 + (tid >> 5);
    const int c    = tid & 31;
    if (node >= Nn) return;

    const float* xrow = x + ((size_t)h * Nn + node) * D;
    float al = 0.f, ar = 0.f;
#pragma unroll
    for (int k = 0; k < D; ++k) {
        const float xv = xrow[k];
        al = fmaf(xv, wl_s[k * D + c], al);
        ar = fmaf(xv, wr_s[k * D + c], ar);
    }
    const size_t o = ((size_t)h * Nn + node) * D + c;
    xlh[o] = (_Float16)al;
    xrh[o] = (_Float16)ar;
}

// ---------------------------------------------------------------------------
// Pass 1: LDS-staged radix partition into 392 coarse bins. Entry=(src<<16)|dst.
// Rank-first single LDS-atomic pass; scan -> lstart; reserve global run;
// stage reorder in LDS; coalesced copy-out to seg1 (CAP-padded windows).
// ---------------------------------------------------------------------------
__global__ __launch_bounds__(TPB1)
void partition_kernel(const int* __restrict__ ei, int* __restrict__ bincur,
                      unsigned* __restrict__ seg1) {
    __shared__ unsigned stage[T1];
    __shared__ int lcur[BPH];      // counts after rank phase
    __shared__ int lstart[BPH];
    __shared__ int gdst[BPH];
    __shared__ int hs[128];

    const int h   = blockIdx.y;
    const int tb  = blockIdx.x * T1;
    const int tid = threadIdx.x;

    for (int i = tid; i < BPH; i += TPB1) lcur[i] = 0;
    __syncthreads();

    const int4* srcp = (const int4*)(ei + (size_t)h * 2 * Ee);
    const int4* dstp = (const int4*)(ei + (size_t)h * 2 * Ee + Ee);

    unsigned ent[EPT];
    unsigned short rk[EPT];
#pragma unroll
    for (int k = 0; k < EPT / 4; ++k) {
        const int e4 = tb + 4 * (k * TPB1 + tid);    // Ee % 4 == 0
        if (e4 < Ee) {
            const int4 s4 = srcp[e4 >> 2];
            const int4 d4 = dstp[e4 >> 2];
            ent[4 * k + 0] = ((unsigned)s4.x << 16) | (unsigned)d4.x;
            ent[4 * k + 1] = ((unsigned)s4.y << 16) | (unsigned)d4.y;
            ent[4 * k + 2] = ((unsigned)s4.z << 16) | (unsigned)d4.z;
            ent[4 * k + 3] = ((unsigned)s4.w << 16) | (unsigned)d4.w;
            rk[4 * k + 0] = (unsigned short)atomicAdd(&lcur[d4.x >> GBITS], 1);
            rk[4 * k + 1] = (unsigned short)atomicAdd(&lcur[d4.y >> GBITS], 1);
            rk[4 * k + 2] = (unsigned short)atomicAdd(&lcur[d4.z >> GBITS], 1);
            rk[4 * k + 3] = (unsigned short)atomicAdd(&lcur[d4.w >> GBITS], 1);
        } else {
            ent[4 * k + 0] = ent[4 * k + 1] = ent[4 * k + 2] = ent[4 * k + 3] = 0xffffffffu;
        }
    }
    __syncthreads();

    // inclusive H-S scan of 98 counts (threads 0..127)
    if (tid < 128) hs[tid] = (tid < BPH) ? lcur[tid] : 0;
    __syncthreads();
    for (int o = 1; o < 128; o <<= 1) {
        int v = 0;
        if (tid < 128 && tid >= o) v = hs[tid - o];
        __syncthreads();
        if (tid < 128) hs[tid] += v;
        __syncthreads();
    }
    if (tid < BPH) {
        lstart[tid] = hs[tid] - lcur[tid];
        if (lcur[tid] > 0) {
            const int g = atomicAdd(&bincur[h * BPH + tid], lcur[tid]);
            gdst[tid] = (h * BPH + tid) * CAP + g;
        }
    }
    __syncthreads();

    // reorder into LDS stage via saved rank
#pragma unroll
    for (int k = 0; k < EPT; ++k) {
        if (ent[k] != 0xffffffffu) {
            const int b = (int)((ent[k] & 0xffffu) >> GBITS);
            stage[lstart[b] + (int)rk[k]] = ent[k];
        }
    }
    __syncthreads();

    const int tot = lstart[BPH - 1] + lcur[BPH - 1];
    for (int i = tid; i < tot; i += TPB1) {
        const unsigned e = stage[i];
        const int b = (int)((e & 0xffffu) >> GBITS);
        seg1[(size_t)gdst[b] + (i - lstart[b])] = e;
    }
}

// ---------------------------------------------------------------------------
// Pass 2: per-bin row sort, 512 threads. 512-row LDS hist + scan; scatter src
// (u16) into the bin's CAP-padded window; emit per-bin-LOCAL roff (+end
// marker) -> no global compaction, no binscan kernel.
// ---------------------------------------------------------------------------
__global__ __launch_bounds__(512)
void rowsort_kernel(const int* __restrict__ bincur, const unsigned* __restrict__ seg1,
                    unsigned short* __restrict__ seg2, int* __restrict__ roff) {
    __shared__ int rcnt[GW];
    __shared__ int rcur[GW];
    const int bin = blockIdx.x;
    const int b   = bin % BPH;
    const int nodebase = b * GW;
    const int cnt  = bincur[bin];
    const size_t base = (size_t)bin * CAP;
    const int tid = threadIdx.x;

    rcnt[tid] = 0;
    __syncthreads();
    for (int i = tid; i < cnt; i += 512)
        atomicAdd(&rcnt[(int)(seg1[base + i] & 0xffffu) - nodebase], 1);
    __syncthreads();

    // inclusive H-S scan in place (512 threads, one per counter)
    const int v = rcnt[tid];
    for (int o = 1; o < GW; o <<= 1) {
        const int a = (tid >= o) ? rcnt[tid - o] : 0;
        __syncthreads();
        rcnt[tid] += a;
        __syncthreads();
    }
    const int excl = rcnt[tid] - v;
    rcur[tid] = excl;
    roff[bin * (GW + 1) + tid] = excl;
    if (tid == GW - 1) roff[bin * (GW + 1) + GW] = excl + v;   // = cnt
    __syncthreads();

    for (int i = tid; i < cnt; i += 512) {
        const unsigned ent = seg1[base + i];
        const int row = (int)(ent & 0xffffu) - nodebase;
        const int p = atomicAdd(&rcur[row], 1);
        seg2[base + p] = (unsigned short)(ent >> 16);
    }
}

// ---------------------------------------------------------------------------
// Accum: one 4-lane group per destination row (8 f16 channels/lane, 16 B
// loads). Packed-f16 add/leaky + v_dot2_f32_f16 logit; fp32 accumulator.
// Register-only, zero atomics. XCD-pair-per-head swizzle.
// ---------------------------------------------------------------------------
__global__ __launch_bounds__(256, 4)
void accum_kernel(const int* __restrict__ roff, const unsigned short* __restrict__ seg2,
                  const _Float16* __restrict__ xlh, const _Float16* __restrict__ xrh,
                  const float* __restrict__ att, const float* __restrict__ bias,
                  float* __restrict__ out) {
    const int tid = threadIdx.x;
    const int l4  = tid & 3;
    const int grp = tid >> 2;                 // 64 rows per block
    const int L   = blockIdx.x;               // grid = 8*BLKH/2 pattern (3128)
    const int h   = (L >> 1) & 3;             // xcd = L&7, head = xcd>>1
    const int ib  = ((L >> 3) << 1) | (L & 1);
    const int n   = ib * 64 + grp;
    if (n >= Nn) return;
    const int hbase = h * Nn;
    const int r     = hbase + n;

    const int gbin = h * BPH + (n >> GBITS);
    const int j0   = n & (GW - 1);
    const int rb   = gbin * (GW + 1);
    const int beg  = roff[rb + j0];
    const int end  = roff[rb + j0 + 1];
    const size_t segbase = (size_t)gbin * CAP;

    // att (f16 pairs) for this lane's 8 channels
    v2h a0, a1, a2, a3;
    {
        const float* ap = att + h * D + l4 * 8;
        a0[0] = (_Float16)ap[0]; a0[1] = (_Float16)ap[1];
        a1[0] = (_Float16)ap[2]; a1[1] = (_Float16)ap[3];
        a2[0] = (_Float16)ap[4]; a2[1] = (_Float16)ap[5];
        a3[0] = (_Float16)ap[6]; a3[1] = (_Float16)ap[7];
    }
    const v2h sl2 = {(_Float16)NEG_SLOPE, (_Float16)NEG_SLOPE};

    U16B xr8; xr8.u = *(const uint4*)(xrh + (size_t)r * D + l4 * 8);

    float ac0 = 0.f, ac1 = 0.f, ac2 = 0.f, ac3 = 0.f;
    float ac4 = 0.f, ac5 = 0.f, ac6 = 0.f, ac7 = 0.f;
    float den = 0.f;

    auto proc = [&](const H8& xg) {
        const v2h h0 = xg.a + xr8.h.a, h1 = xg.b + xr8.h.b;
        const v2h h2 = xg.c + xr8.h.c, h3 = xg.d + xr8.h.d;
        const v2h l0 = __builtin_elementwise_max(h0, h0 * sl2);
        const v2h l1 = __builtin_elementwise_max(h1, h1 * sl2);
        const v2h l2 = __builtin_elementwise_max(h2, h2 * sl2);
        const v2h l3 = __builtin_elementwise_max(h3, h3 * sl2);
        float p;
#ifdef HAS_FDOT2
        p = __builtin_amdgcn_fdot2(l0, a0, 0.f, false);
        p = __builtin_amdgcn_fdot2(l1, a1, p, false);
        p = __builtin_amdgcn_fdot2(l2, a2, p, false);
        p = __builtin_amdgcn_fdot2(l3, a3, p, false);
#else
        p  = (float)l0[0] * (float)a0[0] + (float)l0[1] * (float)a0[1];
        p += (float)l1[0] * (float)a1[0] + (float)l1[1] * (float)a1[1];
        p += (float)l2[0] * (float)a2[0] + (float)l2[1] * (float)a2[1];
        p += (float)l3[0] * (float)a3[0] + (float)l3[1] * (float)a3[1];
#endif
        p += __shfl_xor(p, 1, 4);
        p += __shfl_xor(p, 2, 4);
        const float w = __expf(p);
        ac0 = fmaf(w, (float)xg.a[0], ac0);
        ac1 = fmaf(w, (float)xg.a[1], ac1);
        ac2 = fmaf(w, (float)xg.b[0], ac2);
        ac3 = fmaf(w, (float)xg.b[1], ac3);
        ac4 = fmaf(w, (float)xg.c[0], ac4);
        ac5 = fmaf(w, (float)xg.c[1], ac5);
        ac6 = fmaf(w, (float)xg.d[0], ac6);
        ac7 = fmaf(w, (float)xg.d[1], ac7);
        den += w;
    };

    // self-loop
    {
        U16B xs; xs.u = *(const uint4*)(xlh + (size_t)r * D + l4 * 8);
        proc(xs.h);
    }

    int j = beg;
    for (; j + 4 <= end; j += 4) {
        const int sv = (int)seg2[segbase + j + l4];
#pragma unroll
        for (int k = 0; k < 4; ++k) {
            const int s = __shfl(sv, k, 4);
            U16B xg; xg.u = *(const uint4*)(xlh + (size_t)(hbase + s) * D + l4 * 8);
            proc(xg.h);
        }
    }
    if (j < end) {
        const int m = end - j;
        int idx = j + l4;
        if (idx >= end) idx = end - 1;
        const int sv = (int)seg2[segbase + idx];
        for (int k = 0; k < m; ++k) {
            const int s = __shfl(sv, k, 4);
            U16B xg; xg.u = *(const uint4*)(xlh + (size_t)(hbase + s) * D + l4 * 8);
            proc(xg.h);
        }
    }

    const float* bp = bias + h * D + l4 * 8;
    const float inv = 1.f / den;
    float* op = out + (size_t)n * (Hh * D) + h * D + l4 * 8;
    float4 o0, o1;
    o0.x = ac0 * inv + bp[0]; o0.y = ac1 * inv + bp[1];
    o0.z = ac2 * inv + bp[2]; o0.w = ac3 * inv + bp[3];
    o1.x = ac4 * inv + bp[4]; o1.y = ac5 * inv + bp[5];
    o1.z = ac6 * inv + bp[6]; o1.w = ac7 * inv + bp[7];
    ((float4*)op)[0] = o0;
    ((float4*)op)[1] = o1;
}

extern "C" void kernel_launch(void* const* d_in, const int* in_sizes, int n_in,
                              void* d_out, int out_size, void* d_ws, size_t ws_size,
                              hipStream_t stream) {
    const float* x    = (const float*)d_in[0];
    const int*   ei   = (const int*)d_in[1];
    const float* Wl   = (const float*)d_in[2];
    const float* Wr   = (const float*)d_in[3];
    const float* att  = (const float*)d_in[4];
    const float* bias = (const float*)d_in[5];
    float* out = (float*)d_out;

    // workspace: xlh[6.4M f16] | xrh[6.4M f16] | seg1[NBIN*CAP u32 = 28.9MB]
    //            | seg2[NBIN*CAP u16 = 14.5MB] | bincur[392] | roff[392*513]
    _Float16* xlh  = (_Float16*)d_ws;
    _Float16* xrh  = xlh + (size_t)Hh * Nn * D;
    unsigned* seg1 = (unsigned*)(xrh + (size_t)Hh * Nn * D);
    unsigned short* seg2 = (unsigned short*)(seg1 + (size_t)NBIN * CAP);
    int* bincur = (int*)(seg2 + (size_t)NBIN * CAP);
    int* roff   = bincur + NBIN;

    hipMemsetAsync(bincur, 0, NBIN * sizeof(int), stream);

    dim3 gT((Nn + 7) / 8, Hh);
    transform_kernel<<<gT, 256, 0, stream>>>(x, Wl, Wr, xlh, xrh);

    dim3 gP((Ee + T1 - 1) / T1, Hh);
    partition_kernel<<<gP, TPB1, 0, stream>>>(ei, bincur, seg1);

    rowsort_kernel<<<NBIN, 512, 0, stream>>>(bincur, seg1, seg2, roff);

    accum_kernel<<<4 * BLKH, 256, 0, stream>>>(roff, seg2, xlh, xrh, att, bias, out);
}

// Round 10
// 249.800 us; speedup vs baseline: 13.6858x; 1.1280x over previous
//
#include <hip/hip_runtime.h>

#define NEG_SLOPE 0.2f

static constexpr int Hh   = 4;
static constexpr int Nn   = 50000;
static constexpr int Ee   = 1600000;
static constexpr int D    = 32;

static constexpr int GBITS = 8;                       // 256 nodes per bin
static constexpr int GW    = 1 << GBITS;
static constexpr int BPH   = (Nn + GW - 1) / GW;      // 196 bins/head
static constexpr int NBIN  = Hh * BPH;                // 784 bins
static constexpr int CAP   = 9728;                    // mean 8192 + 17 sigma
static constexpr int T1    = 8192;                    // partition tile (edges)
static constexpr int TPB1  = 512;
static constexpr int EPT   = T1 / TPB1;               // 16 edges/thread
static constexpr int NPT   = (Ee + T1 - 1) / T1;      // 196 tiles/head
static constexpr int NPB   = NPT * Hh;                // 784 partition blocks
static constexpr int NTB   = (Nn / 16) * Hh;          // 12500 transform blocks

typedef _Float16 v2h __attribute__((ext_vector_type(2)));
struct H8 { v2h a, b, c, d; };                        // 8 halves = 16 B
union U16B { uint4 u; H8 h; };

#if defined(__has_builtin)
#if __has_builtin(__builtin_amdgcn_fdot2)
#define HAS_FDOT2 1
#endif
#endif

// ---------------------------------------------------------------------------
// Pass 1: two roles in one launch (block-uniform branch).
//   blocks [0, NPB)        : LDS-staged radix partition of edges into 784 bins
//   blocks [NPB, NPB+NTB)  : xl/xr = x @ W_{l,r} per head, stored f16
// Roles are independent; partition (DS-bound) and transform (VALU-bound)
// co-schedule instead of running serially.
// ---------------------------------------------------------------------------
union SMem {
    struct {
        unsigned stage[T1];          // 32 KB
        int lcur[BPH];
        int lstart[BPH];
        int gdst[BPH];
        int hs[256];
    } p;
    struct {
        float wl[D * D];
        float wr[D * D];
    } t;
};

__global__ __launch_bounds__(TPB1)
void pass1_kernel(const float* __restrict__ x, const float* __restrict__ Wl,
                  const float* __restrict__ Wr, const int* __restrict__ ei,
                  _Float16* __restrict__ xlh, _Float16* __restrict__ xrh,
                  int* __restrict__ bincur, unsigned* __restrict__ seg1) {
    __shared__ SMem sm;
    const int L   = blockIdx.x;
    const int tid = threadIdx.x;

    if (L < NPB) {
        // ------------------- partition role -------------------
        const int h  = L & 3;
        const int tb = (L >> 2) * T1;

        for (int i = tid; i < BPH; i += TPB1) sm.p.lcur[i] = 0;
        __syncthreads();

        const int4* srcp = (const int4*)(ei + (size_t)h * 2 * Ee);
        const int4* dstp = (const int4*)(ei + (size_t)h * 2 * Ee + Ee);

        unsigned ent[EPT];
        unsigned short rk[EPT];
#pragma unroll
        for (int k = 0; k < EPT / 4; ++k) {
            const int e4 = tb + 4 * (k * TPB1 + tid);    // Ee % 4 == 0
            if (e4 < Ee) {
                const int4 s4 = srcp[e4 >> 2];
                const int4 d4 = dstp[e4 >> 2];
                ent[4 * k + 0] = ((unsigned)s4.x << 16) | (unsigned)d4.x;
                ent[4 * k + 1] = ((unsigned)s4.y << 16) | (unsigned)d4.y;
                ent[4 * k + 2] = ((unsigned)s4.z << 16) | (unsigned)d4.z;
                ent[4 * k + 3] = ((unsigned)s4.w << 16) | (unsigned)d4.w;
                rk[4 * k + 0] = (unsigned short)atomicAdd(&sm.p.lcur[d4.x >> GBITS], 1);
                rk[4 * k + 1] = (unsigned short)atomicAdd(&sm.p.lcur[d4.y >> GBITS], 1);
                rk[4 * k + 2] = (unsigned short)atomicAdd(&sm.p.lcur[d4.z >> GBITS], 1);
                rk[4 * k + 3] = (unsigned short)atomicAdd(&sm.p.lcur[d4.w >> GBITS], 1);
            } else {
                ent[4*k+0] = ent[4*k+1] = ent[4*k+2] = ent[4*k+3] = 0xffffffffu;
            }
        }
        __syncthreads();

        // inclusive H-S scan of 196 counts (threads 0..255)
        if (tid < 256) sm.p.hs[tid] = (tid < BPH) ? sm.p.lcur[tid] : 0;
        __syncthreads();
        for (int o = 1; o < 256; o <<= 1) {
            int v = 0;
            if (tid < 256 && tid >= o) v = sm.p.hs[tid - o];
            __syncthreads();
            if (tid < 256) sm.p.hs[tid] += v;
            __syncthreads();
        }
        if (tid < BPH) {
            sm.p.lstart[tid] = sm.p.hs[tid] - sm.p.lcur[tid];
            if (sm.p.lcur[tid] > 0) {
                const int g = atomicAdd(&bincur[h * BPH + tid], sm.p.lcur[tid]);
                sm.p.gdst[tid] = (h * BPH + tid) * CAP + g;
            }
        }
        __syncthreads();

        // reorder into LDS stage via saved rank
#pragma unroll
        for (int k = 0; k < EPT; ++k) {
            if (ent[k] != 0xffffffffu) {
                const int b = (int)((ent[k] & 0xffffu) >> GBITS);
                sm.p.stage[sm.p.lstart[b] + (int)rk[k]] = ent[k];
            }
        }
        __syncthreads();

        const int tot = sm.p.lstart[BPH - 1] + sm.p.lcur[BPH - 1];
        for (int i = tid; i < tot; i += TPB1) {
            const unsigned e = sm.p.stage[i];
            const int b = (int)((e & 0xffffu) >> GBITS);
            seg1[(size_t)sm.p.gdst[b] + (i - sm.p.lstart[b])] = e;
        }
    } else {
        // ------------------- transform role -------------------
        const int t  = L - NPB;
        const int h  = t & 3;
        const int nb = t >> 2;               // 0..3124
        for (int i = tid; i < D * D; i += TPB1) {
            sm.t.wl[i] = Wl[h * D * D + i];
            sm.t.wr[i] = Wr[h * D * D + i];
        }
        __syncthreads();

        const int node = nb * 16 + (tid >> 5);
        const int c    = tid & 31;
        if (node >= Nn) return;

        const float* xrow = x + ((size_t)h * Nn + node) * D;
        float al = 0.f, ar = 0.f;
#pragma unroll
        for (int k = 0; k < D; ++k) {
            const float xv = xrow[k];
            al = fmaf(xv, sm.t.wl[k * D + c], al);
            ar = fmaf(xv, sm.t.wr[k * D + c], ar);
        }
        const size_t o = ((size_t)h * Nn + node) * D + c;
        xlh[o] = (_Float16)al;
        xrh[o] = (_Float16)ar;
    }
}

// ---------------------------------------------------------------------------
// Pass 2 (fused rowsort + accum): one block per bin, 512 threads.
// Phase A: 256-row LDS hist + scan, scatter src (u16) into LDS seg2 (no
//          global seg2 round-trip).
// Phase B: 4-lane groups pull rows from an LDS work-stealing counter
//          (removes max-of-16-Poisson wave divergence waste); packed-f16
//          math, fp32 accumulator, register-only, fused softmax+bias+store.
// XCD-pair-per-head launch swizzle keeps each XCD's gathers on one head's
// 3.2 MB f16 xl slice (L2-resident).
// ---------------------------------------------------------------------------
__global__ __launch_bounds__(512)
void sortaccum_kernel(const int* __restrict__ bincur, const unsigned* __restrict__ seg1,
                      const _Float16* __restrict__ xlh, const _Float16* __restrict__ xrh,
                      const float* __restrict__ att, const float* __restrict__ bias,
                      float* __restrict__ out) {
    __shared__ int rcnt[GW];
    __shared__ int rcur[GW];
    __shared__ int rowbeg[GW + 1];
    __shared__ unsigned short s2[CAP];
    __shared__ int nextrow;

    const int tid = threadIdx.x;
    const int L   = blockIdx.x;                 // 784 = 98 * 8
    const int xcd = L & 7;
    const int h   = xcd >> 1;
    const int b   = ((L >> 3) << 1) | (L & 1);  // 0..195
    const int bin = h * BPH + b;
    const int nodebase = b * GW;
    const int nrows = (Nn - nodebase) < GW ? (Nn - nodebase) : GW;
    const int cnt   = bincur[bin];
    const size_t base = (size_t)bin * CAP;
    const int hbase = h * Nn;

    if (tid < GW) rcnt[tid] = 0;
    if (tid == 0) nextrow = 0;
    __syncthreads();

    for (int i = tid; i < cnt; i += 512)
        atomicAdd(&rcnt[seg1[base + i] & 0xffu], 1);
    __syncthreads();

    // inclusive H-S scan over 256 counters (threads 0..255)
    int v = 0;
    if (tid < GW) v = rcnt[tid];
    for (int o = 1; o < GW; o <<= 1) {
        int a = 0;
        if (tid < GW && tid >= o) a = rcnt[tid - o];
        __syncthreads();
        if (tid < GW) rcnt[tid] += a;
        __syncthreads();
    }
    if (tid < GW) {
        const int excl = rcnt[tid] - v;
        rcur[tid]   = excl;
        rowbeg[tid] = excl;
        if (tid == GW - 1) rowbeg[GW] = excl + v;   // = cnt
    }
    __syncthreads();

    for (int i = tid; i < cnt; i += 512) {
        const unsigned e = seg1[base + i];
        const int p = atomicAdd(&rcur[e & 0xffu], 1);
        s2[p] = (unsigned short)(e >> 16);
    }
    __syncthreads();

    // ------------------- phase B: accumulate -------------------
    const int l4 = tid & 3;

    v2h a0, a1, a2, a3;
    {
        const float* ap = att + h * D + l4 * 8;
        a0[0] = (_Float16)ap[0]; a0[1] = (_Float16)ap[1];
        a1[0] = (_Float16)ap[2]; a1[1] = (_Float16)ap[3];
        a2[0] = (_Float16)ap[4]; a2[1] = (_Float16)ap[5];
        a3[0] = (_Float16)ap[6]; a3[1] = (_Float16)ap[7];
    }
    const v2h sl2 = {(_Float16)NEG_SLOPE, (_Float16)NEG_SLOPE};
    const float* bp = bias + h * D + l4 * 8;

    for (;;) {
        int t0 = 0;
        if (l4 == 0) t0 = atomicAdd(&nextrow, 1);
        const int j = __shfl(t0, 0, 4);
        if (j >= nrows) break;

        const int n = nodebase + j;
        const int r = hbase + n;

        U16B xr8; xr8.u = *(const uint4*)(xrh + (size_t)r * D + l4 * 8);

        float ac0 = 0.f, ac1 = 0.f, ac2 = 0.f, ac3 = 0.f;
        float ac4 = 0.f, ac5 = 0.f, ac6 = 0.f, ac7 = 0.f;
        float den = 0.f;

        auto proc = [&](const H8& xg) {
            const v2h h0 = xg.a + xr8.h.a, h1 = xg.b + xr8.h.b;
            const v2h h2 = xg.c + xr8.h.c, h3 = xg.d + xr8.h.d;
            const v2h l0 = __builtin_elementwise_max(h0, h0 * sl2);
            const v2h l1 = __builtin_elementwise_max(h1, h1 * sl2);
            const v2h l2 = __builtin_elementwise_max(h2, h2 * sl2);
            const v2h l3 = __builtin_elementwise_max(h3, h3 * sl2);
            float p;
#ifdef HAS_FDOT2
            p = __builtin_amdgcn_fdot2(l0, a0, 0.f, false);
            p = __builtin_amdgcn_fdot2(l1, a1, p, false);
            p = __builtin_amdgcn_fdot2(l2, a2, p, false);
            p = __builtin_amdgcn_fdot2(l3, a3, p, false);
#else
            p  = (float)l0[0] * (float)a0[0] + (float)l0[1] * (float)a0[1];
            p += (float)l1[0] * (float)a1[0] + (float)l1[1] * (float)a1[1];
            p += (float)l2[0] * (float)a2[0] + (float)l2[1] * (float)a2[1];
            p += (float)l3[0] * (float)a3[0] + (float)l3[1] * (float)a3[1];
#endif
            p += __shfl_xor(p, 1, 4);
            p += __shfl_xor(p, 2, 4);
            const float w = __expf(p);
            ac0 = fmaf(w, (float)xg.a[0], ac0);
            ac1 = fmaf(w, (float)xg.a[1], ac1);
            ac2 = fmaf(w, (float)xg.b[0], ac2);
            ac3 = fmaf(w, (float)xg.b[1], ac3);
            ac4 = fmaf(w, (float)xg.c[0], ac4);
            ac5 = fmaf(w, (float)xg.c[1], ac5);
            ac6 = fmaf(w, (float)xg.d[0], ac6);
            ac7 = fmaf(w, (float)xg.d[1], ac7);
            den += w;
        };

        // self-loop
        {
            U16B xs; xs.u = *(const uint4*)(xlh + (size_t)r * D + l4 * 8);
            proc(xs.h);
        }

        const int beg = rowbeg[j];
        const int end = rowbeg[j + 1];
        int jj = beg;
        for (; jj + 4 <= end; jj += 4) {
            const int sv = (int)s2[jj + l4];
#pragma unroll
            for (int k = 0; k < 4; ++k) {
                const int s = __shfl(sv, k, 4);
                U16B xg; xg.u = *(const uint4*)(xlh + (size_t)(hbase + s) * D + l4 * 8);
                proc(xg.h);
            }
        }
        if (jj < end) {
            const int m = end - jj;
            int idx = jj + l4;
            if (idx >= end) idx = end - 1;
            const int sv = (int)s2[idx];
            for (int k = 0; k < m; ++k) {
                const int s = __shfl(sv, k, 4);
                U16B xg; xg.u = *(const uint4*)(xlh + (size_t)(hbase + s) * D + l4 * 8);
                proc(xg.h);
            }
        }

        const float inv = 1.f / den;
        float* op = out + (size_t)n * (Hh * D) + h * D + l4 * 8;
        float4 o0, o1;
        o0.x = ac0 * inv + bp[0]; o0.y = ac1 * inv + bp[1];
        o0.z = ac2 * inv + bp[2]; o0.w = ac3 * inv + bp[3];
        o1.x = ac4 * inv + bp[4]; o1.y = ac5 * inv + bp[5];
        o1.z = ac6 * inv + bp[6]; o1.w = ac7 * inv + bp[7];
        ((float4*)op)[0] = o0;
        ((float4*)op)[1] = o1;
    }
}

extern "C" void kernel_launch(void* const* d_in, const int* in_sizes, int n_in,
                              void* d_out, int out_size, void* d_ws, size_t ws_size,
                              hipStream_t stream) {
    const float* x    = (const float*)d_in[0];
    const int*   ei   = (const int*)d_in[1];
    const float* Wl   = (const float*)d_in[2];
    const float* Wr   = (const float*)d_in[3];
    const float* att  = (const float*)d_in[4];
    const float* bias = (const float*)d_in[5];
    float* out = (float*)d_out;

    // workspace: xlh[6.4M f16] | xrh[6.4M f16] | seg1[784*9728 u32 = 30.5MB] | bincur[784]
    _Float16* xlh  = (_Float16*)d_ws;
    _Float16* xrh  = xlh + (size_t)Hh * Nn * D;
    unsigned* seg1 = (unsigned*)(xrh + (size_t)Hh * Nn * D);
    int*      bincur = (int*)(seg1 + (size_t)NBIN * CAP);

    hipMemsetAsync(bincur, 0, NBIN * sizeof(int), stream);

    pass1_kernel<<<NPB + NTB, TPB1, 0, stream>>>(x, Wl, Wr, ei, xlh, xrh, bincur, seg1);

    sortaccum_kernel<<<NBIN, 512, 0, stream>>>(bincur, seg1, xlh, xrh, att, bias, out);
}